// Round 1
// baseline (5123.697 us; speedup 1.0000x reference)
//
#include <hip/hip_runtime.h>
#include <cstdint>
#include <cstddef>

typedef __attribute__((ext_vector_type(4))) float f32x4;
typedef __attribute__((ext_vector_type(8))) short s16x8;
typedef __attribute__((ext_vector_type(4))) unsigned short u16x4;
typedef __attribute__((ext_vector_type(2))) unsigned short u16x2;

#define NLAYER 8
#define DM 1024
#define NTOK 4096
#define DFF2 4096
#define NV 50257
#define NVP 50304

__device__ __forceinline__ unsigned short f2bf(float f) {
  unsigned int u = __float_as_uint(f);
  u = u + 0x7fffu + ((u >> 16) & 1u);
  return (unsigned short)(u >> 16);
}

// CK-style generic->AS1/AS3 conversion for global_load_lds (width 16B).
__device__ __forceinline__ void gload_lds16(const void* gp, void* lp) {
  const __attribute__((address_space(1))) unsigned int* g =
      reinterpret_cast<const __attribute__((address_space(1))) unsigned int*>(
          reinterpret_cast<uintptr_t>(gp));
  __attribute__((address_space(3))) unsigned int* l =
      reinterpret_cast<__attribute__((address_space(3))) unsigned int*>(
          (unsigned int)(uintptr_t)lp);
  __builtin_amdgcn_global_load_lds(g, l, 16, 0, 0);
}

// ---------------- weight convert + transpose: out[n][k] = bf16(in[k][n]) ----
__global__ void __launch_bounds__(256) convT_k(const float* __restrict__ in,
                                               unsigned short* __restrict__ out,
                                               int K, int N, int Np) {
  __shared__ float tile[64][65];
  const int n0 = blockIdx.x * 64, k0 = blockIdx.y * 64;
  const float* inp = in + (size_t)blockIdx.z * K * N;
  unsigned short* outp = out + (size_t)blockIdx.z * Np * K;
  const int tid = threadIdx.x;
#pragma unroll
  for (int p = 0; p < 16; ++p) {
    const int r = p * 4 + (tid >> 6);
    const int cc = tid & 63;
    const int gn = n0 + cc;
    tile[r][cc] = (gn < N) ? inp[(size_t)(k0 + r) * N + gn] : 0.f;
  }
  __syncthreads();
#pragma unroll
  for (int p = 0; p < 8; ++p) {
    const int lin = p * 256 + tid;
    const int rn = lin >> 5;
    const int c2 = (lin & 31) * 2;
    u16x2 o;
    o[0] = f2bf(tile[c2][rn]);
    o[1] = f2bf(tile[c2 + 1][rn]);
    *(u16x2*)&outp[(size_t)(n0 + rn) * K + k0 + c2] = o;
  }
}

// ---------------- embedding: x = wte[idx] + wpe[t] ----------------
__global__ void __launch_bounds__(256) embed_k(const int* __restrict__ idx,
                                               const float* __restrict__ wte,
                                               const float* __restrict__ wpe,
                                               float* __restrict__ X) {
  const int tok = blockIdx.x;
  const int t = tok & 1023;
  const int id = idx[tok];
  const int c = threadIdx.x * 4;
  f32x4 a = *(const f32x4*)&wte[(size_t)id * DM + c];
  f32x4 p = *(const f32x4*)&wpe[(size_t)t * DM + c];
  a = a + p;
  *(f32x4*)&X[(size_t)tok * DM + c] = a;
}

// ---------------- LayerNorm: f32 in -> bf16 out ----------------
__global__ void __launch_bounds__(256) ln_k(const float* __restrict__ X,
                                            const float* __restrict__ W,
                                            const float* __restrict__ Bp,
                                            unsigned short* __restrict__ O) {
  const int row = blockIdx.x, tid = threadIdx.x;
  const size_t base = (size_t)row * DM;
  f32x4 v = *(const f32x4*)&X[base + tid * 4];
  float s = v[0] + v[1] + v[2] + v[3];
  float q = v[0] * v[0] + v[1] * v[1] + v[2] * v[2] + v[3] * v[3];
#pragma unroll
  for (int m = 1; m < 64; m <<= 1) {
    s += __shfl_xor(s, m);
    q += __shfl_xor(q, m);
  }
  __shared__ float ps[4], pq[4];
  const int wv = tid >> 6;
  if ((tid & 63) == 0) { ps[wv] = s; pq[wv] = q; }
  __syncthreads();
  s = ps[0] + ps[1] + ps[2] + ps[3];
  q = pq[0] + pq[1] + pq[2] + pq[3];
  const float mu = s * (1.f / DM);
  const float var = q * (1.f / DM) - mu * mu;
  const float rstd = rsqrtf(var + 1e-5f);
  f32x4 w = *(const f32x4*)&W[tid * 4];
  f32x4 bb = *(const f32x4*)&Bp[tid * 4];
  u16x4 o;
#pragma unroll
  for (int j = 0; j < 4; ++j) o[j] = f2bf((v[j] - mu) * rstd * w[j] + bb[j]);
  *(u16x4*)&O[base + tid * 4] = o;
}

// ---------------- GEMM: C[M,N] = A[M,K](bf16) x Bt[N,K]^T(bf16) + epilogue --
// 128x128 tile, BK=32, 4 waves, 16x16x32 bf16 MFMA (m97 structure).
__global__ void __launch_bounds__(256) gemm_k(
    const unsigned short* __restrict__ A, const unsigned short* __restrict__ Bt,
    const float* __restrict__ bias, const float* __restrict__ resid,
    float* __restrict__ outF, unsigned short* __restrict__ outB,
    int M, int N, int K, int ldc, int relu) {
  __shared__ __align__(16) unsigned short lA[128 * 32];
  __shared__ __align__(16) unsigned short lB[128 * 32];
  const int tid = threadIdx.x;
  const int wv = tid >> 6, lane = tid & 63;
  const int row0 = blockIdx.y * 128, col0 = blockIdx.x * 128;
  const int wr = wv >> 1, wc = wv & 1;

  f32x4 acc[4][4] = {};

  const int sRow = tid >> 2;
  const int sCol = (tid & 3) * 8;
  const unsigned short* gA = A + (size_t)(row0 + sRow) * K + sCol;
  const unsigned short* gB = Bt + (size_t)(col0 + sRow) * K + sCol;
  unsigned short* lAd = lA + wv * 512;  // linear dest: wave-uniform + lane*16B
  unsigned short* lBd = lB + wv * 512;
  const size_t step64 = (size_t)64 * K;

  for (int kt = 0; kt < K; kt += 32) {
    gload_lds16(gA + kt, lAd);
    gload_lds16(gA + kt + step64, lAd + 2048);
    gload_lds16(gB + kt, lBd);
    gload_lds16(gB + kt + step64, lBd + 2048);
    __syncthreads();  // drains vmcnt -> LDS tiles ready
    const int kb = (lane >> 4) * 8;
    const int rA = (wr * 64 + (lane & 15)) * 32 + kb;
    const int rB = (wc * 64 + (lane & 15)) * 32 + kb;
    s16x8 af[4], bfr[4];
#pragma unroll
    for (int m = 0; m < 4; ++m) af[m] = *(const s16x8*)&lA[rA + m * 512];
#pragma unroll
    for (int n = 0; n < 4; ++n) bfr[n] = *(const s16x8*)&lB[rB + n * 512];
#pragma unroll
    for (int m = 0; m < 4; ++m)
#pragma unroll
      for (int n = 0; n < 4; ++n)
        acc[m][n] = __builtin_amdgcn_mfma_f32_16x16x32_bf16(af[m], bfr[n],
                                                            acc[m][n], 0, 0, 0);
    __syncthreads();  // all reads done before next stage overwrites
  }

  const int baseRow = row0 + wr * 64 + ((lane >> 4) * 4);
  const int baseCol = col0 + wc * 64 + (lane & 15);
#pragma unroll
  for (int m = 0; m < 4; ++m) {
#pragma unroll
    for (int n = 0; n < 4; ++n) {
      const int colc = baseCol + n * 16;
      if (colc < N) {
        const float bv = bias ? bias[colc] : 0.f;
#pragma unroll
        for (int r = 0; r < 4; ++r) {
          const int rowc = baseRow + m * 16 + r;
          float v = acc[m][n][r] + bv;
          if (resid) v += resid[(size_t)rowc * ldc + colc];
          if (relu) v = fmaxf(v, 0.f);
          if (outF) outF[(size_t)rowc * ldc + colc] = v;
          if (outB) outB[(size_t)rowc * ldc + colc] = f2bf(v);
        }
      }
    }
  }
}

// ---------------- V transpose: V[B*T, D] -> Vt[bh][hs][t] ----------------
__global__ void __launch_bounds__(256) vtrans_k(const unsigned short* __restrict__ V,
                                                unsigned short* __restrict__ Vt) {
  __shared__ unsigned short tile[64][72];
  const int tt = blockIdx.x, bh = blockIdx.y;
  const int b = bh >> 4, h = bh & 15;
  const int tid = threadIdx.x;
#pragma unroll
  for (int p = 0; p < 2; ++p) {
    const int r = (tid >> 3) + p * 32;
    const int c8 = (tid & 7) * 8;
    s16x8 v = *(const s16x8*)&V[((size_t)(b * 1024 + tt * 64 + r)) * DM + h * 64 + c8];
#pragma unroll
    for (int j = 0; j < 8; ++j) tile[r][c8 + j] = (unsigned short)v[j];
  }
  __syncthreads();
#pragma unroll
  for (int p = 0; p < 2; ++p) {
    const int hs = (tid >> 3) + p * 32;
    const int t8 = (tid & 7) * 8;
    s16x8 o;
#pragma unroll
    for (int j = 0; j < 8; ++j) o[j] = (short)tile[t8 + j][hs];
    *(s16x8*)&Vt[((size_t)(bh * 64 + hs)) * 1024 + tt * 64 + t8] = o;
  }
}

// ---------------- fused causal attention (flash-style) ----------------
// grid: (qtile 16, bh 64); block 256 = 4 waves; each wave owns 16 q-rows.
__global__ void __launch_bounds__(256) attn_k(const unsigned short* __restrict__ Q,
                                              const unsigned short* __restrict__ Kb,
                                              const unsigned short* __restrict__ Vt,
                                              unsigned short* __restrict__ O) {
  const int qt = blockIdx.x;
  const int bh = blockIdx.y;
  const int b = bh >> 4, h = bh & 15;
  const int tid = threadIdx.x, wv = tid >> 6, lane = tid & 63;
  const int g = lane >> 4, c = lane & 15;
  __shared__ __align__(16) unsigned short lP[4][16 * 64];
  const int qw0 = qt * 64 + wv * 16;
  s16x8 qf0, qf1;
  {
    const size_t qoff = ((size_t)(b * 1024 + qw0 + c)) * DM + h * 64 + g * 8;
    qf0 = *(const s16x8*)&Q[qoff];
    qf1 = *(const s16x8*)&Q[qoff + 32];
  }
  f32x4 acc[4] = {};
  float mrun[4], lrun[4];
#pragma unroll
  for (int r = 0; r < 4; ++r) { mrun[r] = -1e30f; lrun[r] = 0.f; }

  for (int kt = 0; kt <= qt; ++kt) {
    f32x4 s[4] = {};
#pragma unroll
    for (int n = 0; n < 4; ++n) {
      const size_t koff = ((size_t)(b * 1024 + kt * 64 + n * 16 + c)) * DM + h * 64 + g * 8;
      s16x8 k0 = *(const s16x8*)&Kb[koff];
      s16x8 k1 = *(const s16x8*)&Kb[koff + 32];
      s[n] = __builtin_amdgcn_mfma_f32_16x16x32_bf16(qf0, k0, s[n], 0, 0, 0);
      s[n] = __builtin_amdgcn_mfma_f32_16x16x32_bf16(qf1, k1, s[n], 0, 0, 0);
    }
    float p[4][4], mx[4] = {-1e30f, -1e30f, -1e30f, -1e30f};
#pragma unroll
    for (int n = 0; n < 4; ++n)
#pragma unroll
      for (int r = 0; r < 4; ++r) {
        const int qrow = qw0 + g * 4 + r;
        const int key = kt * 64 + n * 16 + c;
        float v = s[n][r] * 0.125f;
        if (key > qrow) v = -1e30f;
        p[n][r] = v;
        mx[r] = fmaxf(mx[r], v);
      }
#pragma unroll
    for (int r = 0; r < 4; ++r)
#pragma unroll
      for (int m = 1; m <= 8; m <<= 1) mx[r] = fmaxf(mx[r], __shfl_xor(mx[r], m));
    float al[4], rs[4];
#pragma unroll
    for (int r = 0; r < 4; ++r) {
      const float mn = fmaxf(mrun[r], mx[r]);
      al[r] = __expf(mrun[r] - mn);
      mrun[r] = mn;
      rs[r] = 0.f;
    }
#pragma unroll
    for (int n = 0; n < 4; ++n)
#pragma unroll
      for (int r = 0; r < 4; ++r) {
        const float e = __expf(p[n][r] - mrun[r]);
        p[n][r] = e;
        rs[r] += e;
      }
#pragma unroll
    for (int r = 0; r < 4; ++r) {
#pragma unroll
      for (int m = 1; m <= 8; m <<= 1) rs[r] += __shfl_xor(rs[r], m);
      lrun[r] = lrun[r] * al[r] + rs[r];
    }
#pragma unroll
    for (int n = 0; n < 4; ++n)
#pragma unroll
      for (int r = 0; r < 4; ++r) acc[n][r] *= al[r];
    __syncthreads();  // prior PV reads of lP complete
#pragma unroll
    for (int n = 0; n < 4; ++n)
#pragma unroll
      for (int r = 0; r < 4; ++r)
        lP[wv][(g * 4 + r) * 64 + n * 16 + c] = f2bf(p[n][r]);
    __syncthreads();  // P visible
    s16x8 pa0 = *(const s16x8*)&lP[wv][c * 64 + g * 8];
    s16x8 pa1 = *(const s16x8*)&lP[wv][c * 64 + 32 + g * 8];
#pragma unroll
    for (int n = 0; n < 4; ++n) {
      const size_t voff = ((size_t)(bh * 64 + n * 16 + c)) * 1024 + kt * 64 + g * 8;
      s16x8 v0 = *(const s16x8*)&Vt[voff];
      s16x8 v1 = *(const s16x8*)&Vt[voff + 32];
      acc[n] = __builtin_amdgcn_mfma_f32_16x16x32_bf16(pa0, v0, acc[n], 0, 0, 0);
      acc[n] = __builtin_amdgcn_mfma_f32_16x16x32_bf16(pa1, v1, acc[n], 0, 0, 0);
    }
  }
#pragma unroll
  for (int n = 0; n < 4; ++n)
#pragma unroll
    for (int r = 0; r < 4; ++r) {
      const size_t row = (size_t)(b * 1024 + qw0 + g * 4 + r);
      O[row * DM + h * 64 + n * 16 + c] = f2bf(acc[n][r] / lrun[r]);
    }
}

// ---------------- host ----------------
extern "C" void kernel_launch(void* const* d_in, const int* in_sizes, int n_in,
                              void* d_out, int out_size, void* d_ws, size_t ws_size,
                              hipStream_t stream) {
  const int* idx = (const int*)d_in[0];
  const float* wte = (const float*)d_in[1];
  const float* wpe = (const float*)d_in[2];
  const float* wq = (const float*)d_in[3];
  const float* wk = (const float*)d_in[4];
  const float* wv = (const float*)d_in[5];
  const float* wo = (const float*)d_in[6];
  const float* bo = (const float*)d_in[7];
  const float* ln1w = (const float*)d_in[8];
  const float* ln1b = (const float*)d_in[9];
  const float* ln2w = (const float*)d_in[10];
  const float* ln2b = (const float*)d_in[11];
  const float* w1 = (const float*)d_in[12];
  const float* b1 = (const float*)d_in[13];
  const float* w2 = (const float*)d_in[14];
  const float* b2 = (const float*)d_in[15];
  const float* lnfw = (const float*)d_in[16];
  const float* lnfb = (const float*)d_in[17];
  const float* wlm = (const float*)d_in[18];
  const float* blm = (const float*)d_in[19];
  float* out = (float*)d_out;

  char* ws = (char*)d_ws;
  size_t off = 0;
  auto alloc = [&](size_t bytes) -> void* {
    void* p = ws + off;
    off += (bytes + 255) & ~(size_t)255;
    return p;
  };
  unsigned short* wqT = (unsigned short*)alloc((size_t)NLAYER * DM * DM * 2);
  unsigned short* wkT = (unsigned short*)alloc((size_t)NLAYER * DM * DM * 2);
  unsigned short* wvT = (unsigned short*)alloc((size_t)NLAYER * DM * DM * 2);
  unsigned short* woT = (unsigned short*)alloc((size_t)NLAYER * DM * DM * 2);
  unsigned short* w1T = (unsigned short*)alloc((size_t)NLAYER * DM * DFF2 * 2);
  unsigned short* w2T = (unsigned short*)alloc((size_t)NLAYER * DM * DFF2 * 2);
  // wlmT aliases w1T+w2T (dead after the layer loop): 103MB <= 128MB
  unsigned short* wlmT = w1T;
  float* X = (float*)alloc((size_t)NTOK * DM * 4);
  unsigned short* Hb = (unsigned short*)alloc((size_t)NTOK * DM * 2);
  unsigned short* Qb = (unsigned short*)alloc((size_t)NTOK * DM * 2);
  unsigned short* Kbuf = (unsigned short*)alloc((size_t)NTOK * DM * 2);
  unsigned short* Vb = (unsigned short*)alloc((size_t)NTOK * DM * 2);
  unsigned short* VtB = (unsigned short*)alloc((size_t)NTOK * DM * 2);
  unsigned short* Ab = (unsigned short*)alloc((size_t)NTOK * DM * 2);
  unsigned short* Mid = (unsigned short*)alloc((size_t)NTOK * DFF2 * 2);

  // weight conversions (per-call; deterministic)
  convT_k<<<dim3(16, 16, 8), 256, 0, stream>>>(wq, wqT, DM, DM, DM);
  convT_k<<<dim3(16, 16, 8), 256, 0, stream>>>(wk, wkT, DM, DM, DM);
  convT_k<<<dim3(16, 16, 8), 256, 0, stream>>>(wv, wvT, DM, DM, DM);
  convT_k<<<dim3(16, 16, 8), 256, 0, stream>>>(wo, woT, DM, DM, DM);
  convT_k<<<dim3(64, 16, 8), 256, 0, stream>>>(w1, w1T, DM, DFF2, DFF2);
  convT_k<<<dim3(16, 64, 8), 256, 0, stream>>>(w2, w2T, DFF2, DM, DM);

  embed_k<<<dim3(NTOK), 256, 0, stream>>>(idx, wte, wpe, X);

  for (int i = 0; i < NLAYER; ++i) {
    const size_t wOff = (size_t)i * DM * DM;
    const size_t fOff = (size_t)i * DM * DFF2;
    ln_k<<<dim3(NTOK), 256, 0, stream>>>(X, ln1w + i * DM, ln1b + i * DM, Hb);
    gemm_k<<<dim3(8, 32), 256, 0, stream>>>(Hb, wqT + wOff, nullptr, nullptr,
                                            nullptr, Qb, NTOK, DM, DM, DM, 0);
    gemm_k<<<dim3(8, 32), 256, 0, stream>>>(Hb, wkT + wOff, nullptr, nullptr,
                                            nullptr, Kbuf, NTOK, DM, DM, DM, 0);
    gemm_k<<<dim3(8, 32), 256, 0, stream>>>(Hb, wvT + wOff, nullptr, nullptr,
                                            nullptr, Vb, NTOK, DM, DM, DM, 0);
    vtrans_k<<<dim3(16, 64), 256, 0, stream>>>(Vb, VtB);
    attn_k<<<dim3(16, 64), 256, 0, stream>>>(Qb, Kbuf, VtB, Ab);
    gemm_k<<<dim3(8, 32), 256, 0, stream>>>(Ab, woT + wOff, bo + i * DM, X, X,
                                            nullptr, NTOK, DM, DM, DM, 0);
    ln_k<<<dim3(NTOK), 256, 0, stream>>>(X, ln2w + i * DM, ln2b + i * DM, Hb);
    gemm_k<<<dim3(32, 32), 256, 0, stream>>>(Hb, w1T + fOff, b1 + i * DFF2,
                                             nullptr, nullptr, Mid, NTOK, DFF2,
                                             DM, DFF2, 1);
    gemm_k<<<dim3(8, 32), 256, 0, stream>>>(Mid, w2T + fOff, b2 + i * DM, X, X,
                                            nullptr, NTOK, DM, DFF2, DM, 0);
  }

  // LM head: convert wlm (aliases dead w1T/w2T region), final LN, big GEMM
  convT_k<<<dim3(786, 16, 1), 256, 0, stream>>>(wlm, wlmT, DM, NV, NVP);
  ln_k<<<dim3(NTOK), 256, 0, stream>>>(X, lnfw, lnfb, Hb);
  gemm_k<<<dim3(393, 32), 256, 0, stream>>>(Hb, wlmT, blm, nullptr, out, nullptr,
                                            NTOK, NV, DM, NV, 0);
}

// Round 2
// 4334.859 us; speedup vs baseline: 1.1820x; 1.1820x over previous
//
#include <hip/hip_runtime.h>
#include <cstdint>
#include <cstddef>

typedef __attribute__((ext_vector_type(4))) float f32x4;
typedef __attribute__((ext_vector_type(8))) short s16x8;
typedef __attribute__((ext_vector_type(4))) unsigned short u16x4;
typedef __attribute__((ext_vector_type(2))) unsigned short u16x2;

#define NLAYER 8
#define DM 1024
#define NTOK 4096
#define DFF2 4096
#define NV 50257
#define NVP 50304

__device__ __forceinline__ unsigned short f2bf(float f) {
  unsigned int u = __float_as_uint(f);
  u = u + 0x7fffu + ((u >> 16) & 1u);
  return (unsigned short)(u >> 16);
}

// CK-style generic->AS1/AS3 conversion for global_load_lds (width 16B).
__device__ __forceinline__ void gload_lds16(const void* gp, void* lp) {
  const __attribute__((address_space(1))) unsigned int* g =
      reinterpret_cast<const __attribute__((address_space(1))) unsigned int*>(
          reinterpret_cast<uintptr_t>(gp));
  __attribute__((address_space(3))) unsigned int* l =
      reinterpret_cast<__attribute__((address_space(3))) unsigned int*>(
          (unsigned int)(uintptr_t)lp);
  __builtin_amdgcn_global_load_lds(g, l, 16, 0, 0);
}

// ---------------- weight convert + transpose: out[n][k] = bf16(in[k][n]) ----
__global__ void __launch_bounds__(256) convT_k(const float* __restrict__ in,
                                               unsigned short* __restrict__ out,
                                               int K, int N, size_t zStride) {
  __shared__ float tile[64][65];
  const int n0 = blockIdx.x * 64, k0 = blockIdx.y * 64;
  const float* inp = in + (size_t)blockIdx.z * K * N;
  unsigned short* outp = out + (size_t)blockIdx.z * zStride;
  const int tid = threadIdx.x;
#pragma unroll
  for (int p = 0; p < 16; ++p) {
    const int r = p * 4 + (tid >> 6);
    const int cc = tid & 63;
    const int gn = n0 + cc;
    tile[r][cc] = (gn < N) ? inp[(size_t)(k0 + r) * N + gn] : 0.f;
  }
  __syncthreads();
#pragma unroll
  for (int p = 0; p < 8; ++p) {
    const int lin = p * 256 + tid;
    const int rn = lin >> 5;
    const int c2 = (lin & 31) * 2;
    u16x2 o;
    o[0] = f2bf(tile[c2][rn]);
    o[1] = f2bf(tile[c2 + 1][rn]);
    *(u16x2*)&outp[(size_t)(n0 + rn) * K + k0 + c2] = o;
  }
}

// ---------------- embedding: x = wte[idx] + wpe[t] ----------------
__global__ void __launch_bounds__(256) embed_k(const int* __restrict__ idx,
                                               const float* __restrict__ wte,
                                               const float* __restrict__ wpe,
                                               float* __restrict__ X) {
  const int tok = blockIdx.x;
  const int t = tok & 1023;
  const int id = idx[tok];
  const int c = threadIdx.x * 4;
  f32x4 a = *(const f32x4*)&wte[(size_t)id * DM + c];
  f32x4 p = *(const f32x4*)&wpe[(size_t)t * DM + c];
  a = a + p;
  *(f32x4*)&X[(size_t)tok * DM + c] = a;
}

// ---------------- LayerNorm: f32 in -> bf16 out ----------------
__global__ void __launch_bounds__(256) ln_k(const float* __restrict__ X,
                                            const float* __restrict__ W,
                                            const float* __restrict__ Bp,
                                            unsigned short* __restrict__ O) {
  const int row = blockIdx.x, tid = threadIdx.x;
  const size_t base = (size_t)row * DM;
  f32x4 v = *(const f32x4*)&X[base + tid * 4];
  float s = v[0] + v[1] + v[2] + v[3];
  float q = v[0] * v[0] + v[1] * v[1] + v[2] * v[2] + v[3] * v[3];
#pragma unroll
  for (int m = 1; m < 64; m <<= 1) {
    s += __shfl_xor(s, m);
    q += __shfl_xor(q, m);
  }
  __shared__ float ps[4], pq[4];
  const int wv = tid >> 6;
  if ((tid & 63) == 0) { ps[wv] = s; pq[wv] = q; }
  __syncthreads();
  s = ps[0] + ps[1] + ps[2] + ps[3];
  q = pq[0] + pq[1] + pq[2] + pq[3];
  const float mu = s * (1.f / DM);
  const float var = q * (1.f / DM) - mu * mu;
  const float rstd = rsqrtf(var + 1e-5f);
  f32x4 w = *(const f32x4*)&W[tid * 4];
  f32x4 bb = *(const f32x4*)&Bp[tid * 4];
  u16x4 o;
#pragma unroll
  for (int j = 0; j < 4; ++j) o[j] = f2bf((v[j] - mu) * rstd * w[j] + bb[j]);
  *(u16x4*)&O[base + tid * 4] = o;
}

// ---------------- residual reduce: X += bias + P0 + P1 ----------------
__global__ void __launch_bounds__(256) reduce2_k(float* __restrict__ X,
                                                 const float* __restrict__ bias,
                                                 const float* __restrict__ P0,
                                                 const float* __restrict__ P1) {
  const size_t i = (size_t)blockIdx.x * DM + threadIdx.x * 4;
  f32x4 x = *(f32x4*)&X[i];
  f32x4 b = *(const f32x4*)&bias[threadIdx.x * 4];
  f32x4 a = *(const f32x4*)&P0[i];
  f32x4 c = *(const f32x4*)&P1[i];
  x = x + b + a + c;
  *(f32x4*)&X[i] = x;
}

// ---------------- GEMM: C[M,N] = A[M,K](bf16) x Bt[N,K]^T(bf16) + epilogue --
// 128x128 tile, BK=32, 4 waves, 16x16x32 bf16 MFMA (m97 structure).
// blockIdx.z = K-split chunk (partials to outF + z*M*ldc, no epilogue fusing).
// XCD-aware bijective swizzle + column-major decomp: each XCD owns a run of
// consecutive bx (B-tiles) -> B panel L2-resident. Requires nwg % 8 == 0.
__global__ void __launch_bounds__(256) gemm_k(
    const unsigned short* __restrict__ A, const unsigned short* __restrict__ Bt,
    const float* __restrict__ bias, const float* __restrict__ resid,
    float* __restrict__ outF, unsigned short* __restrict__ outB,
    int M, int N, int K, int lda, int ldc, int relu) {
  __shared__ __align__(16) unsigned short lA[128 * 32];
  __shared__ __align__(16) unsigned short lB[128 * 32];
  const int tid = threadIdx.x;
  const int wv = tid >> 6, lane = tid & 63;

  const int lin = blockIdx.y * gridDim.x + blockIdx.x;
  const int nwg = gridDim.x * gridDim.y;
  const int wg = (lin & 7) * (nwg >> 3) + (lin >> 3);
  const int bx = wg / gridDim.y;
  const int by = wg - bx * gridDim.y;
  const int row0 = by * 128, col0 = bx * 128;
  const int wr = wv >> 1, wc = wv & 1;

  const int z = blockIdx.z;
  A += (size_t)z * K;
  Bt += (size_t)z * K;
  if (gridDim.z > 1) outF += (size_t)z * M * ldc;

  f32x4 acc[4][4] = {};

  const int sRow = tid >> 2;
  const int sCol = (tid & 3) * 8;
  const unsigned short* gA = A + (size_t)(row0 + sRow) * lda + sCol;
  const unsigned short* gB = Bt + (size_t)(col0 + sRow) * lda + sCol;
  unsigned short* lAd = lA + wv * 512;  // linear dest: wave-uniform + lane*16B
  unsigned short* lBd = lB + wv * 512;
  const size_t step64 = (size_t)64 * lda;

  for (int kt = 0; kt < K; kt += 32) {
    gload_lds16(gA + kt, lAd);
    gload_lds16(gA + kt + step64, lAd + 2048);
    gload_lds16(gB + kt, lBd);
    gload_lds16(gB + kt + step64, lBd + 2048);
    __syncthreads();  // drains vmcnt -> LDS tiles ready
    const int kb = (lane >> 4) * 8;
    const int rA = (wr * 64 + (lane & 15)) * 32 + kb;
    const int rB = (wc * 64 + (lane & 15)) * 32 + kb;
    s16x8 af[4], bfr[4];
#pragma unroll
    for (int m = 0; m < 4; ++m) af[m] = *(const s16x8*)&lA[rA + m * 512];
#pragma unroll
    for (int n = 0; n < 4; ++n) bfr[n] = *(const s16x8*)&lB[rB + n * 512];
#pragma unroll
    for (int m = 0; m < 4; ++m)
#pragma unroll
      for (int n = 0; n < 4; ++n)
        acc[m][n] = __builtin_amdgcn_mfma_f32_16x16x32_bf16(af[m], bfr[n],
                                                            acc[m][n], 0, 0, 0);
    __syncthreads();  // all reads done before next stage overwrites
  }

  const int baseRow = row0 + wr * 64 + ((lane >> 4) * 4);
  const int baseCol = col0 + wc * 64 + (lane & 15);
#pragma unroll
  for (int m = 0; m < 4; ++m) {
#pragma unroll
    for (int n = 0; n < 4; ++n) {
      const int colc = baseCol + n * 16;
      if (colc < N) {
        const float bv = bias ? bias[colc] : 0.f;
#pragma unroll
        for (int r = 0; r < 4; ++r) {
          const int rowc = baseRow + m * 16 + r;
          float v = acc[m][n][r] + bv;
          if (resid) v += resid[(size_t)rowc * ldc + colc];
          if (relu) v = fmaxf(v, 0.f);
          if (outF) outF[(size_t)rowc * ldc + colc] = v;
          if (outB) outB[(size_t)rowc * ldc + colc] = f2bf(v);
        }
      }
    }
  }
}

// ---------------- V transpose: V[B*T, ldv] -> Vt[bh][hs][t] ----------------
__global__ void __launch_bounds__(256) vtrans_k(const unsigned short* __restrict__ V,
                                                unsigned short* __restrict__ Vt,
                                                int ldv) {
  __shared__ unsigned short tile[64][72];
  const int tt = blockIdx.x, bh = blockIdx.y;
  const int b = bh >> 4, h = bh & 15;
  const int tid = threadIdx.x;
#pragma unroll
  for (int p = 0; p < 2; ++p) {
    const int r = (tid >> 3) + p * 32;
    const int c8 = (tid & 7) * 8;
    s16x8 v = *(const s16x8*)&V[((size_t)(b * 1024 + tt * 64 + r)) * ldv + h * 64 + c8];
#pragma unroll
    for (int j = 0; j < 8; ++j) tile[r][c8 + j] = (unsigned short)v[j];
  }
  __syncthreads();
#pragma unroll
  for (int p = 0; p < 2; ++p) {
    const int hs = (tid >> 3) + p * 32;
    const int t8 = (tid & 7) * 8;
    s16x8 o;
#pragma unroll
    for (int j = 0; j < 8; ++j) o[j] = (short)tile[t8 + j][hs];
    *(s16x8*)&Vt[((size_t)(bh * 64 + hs)) * 1024 + tt * 64 + t8] = o;
  }
}

// ---------------- fused causal attention (flash-style) ----------------
// grid: (qtile 16, bh 64); block 256 = 4 waves; each wave owns 16 q-rows.
__global__ void __launch_bounds__(256) attn_k(const unsigned short* __restrict__ Q,
                                              const unsigned short* __restrict__ Kb,
                                              const unsigned short* __restrict__ Vt,
                                              unsigned short* __restrict__ O,
                                              int ldq) {
  const int qt = blockIdx.x;
  const int bh = blockIdx.y;
  const int b = bh >> 4, h = bh & 15;
  const int tid = threadIdx.x, wv = tid >> 6, lane = tid & 63;
  const int g = lane >> 4, c = lane & 15;
  __shared__ __align__(16) unsigned short lP[4][16 * 64];
  const int qw0 = qt * 64 + wv * 16;
  s16x8 qf0, qf1;
  {
    const size_t qoff = ((size_t)(b * 1024 + qw0 + c)) * ldq + h * 64 + g * 8;
    qf0 = *(const s16x8*)&Q[qoff];
    qf1 = *(const s16x8*)&Q[qoff + 32];
  }
  f32x4 acc[4] = {};
  float mrun[4], lrun[4];
#pragma unroll
  for (int r = 0; r < 4; ++r) { mrun[r] = -1e30f; lrun[r] = 0.f; }

  for (int kt = 0; kt <= qt; ++kt) {
    f32x4 s[4] = {};
#pragma unroll
    for (int n = 0; n < 4; ++n) {
      const size_t koff = ((size_t)(b * 1024 + kt * 64 + n * 16 + c)) * ldq + h * 64 + g * 8;
      s16x8 k0 = *(const s16x8*)&Kb[koff];
      s16x8 k1 = *(const s16x8*)&Kb[koff + 32];
      s[n] = __builtin_amdgcn_mfma_f32_16x16x32_bf16(qf0, k0, s[n], 0, 0, 0);
      s[n] = __builtin_amdgcn_mfma_f32_16x16x32_bf16(qf1, k1, s[n], 0, 0, 0);
    }
    float p[4][4], mx[4] = {-1e30f, -1e30f, -1e30f, -1e30f};
#pragma unroll
    for (int n = 0; n < 4; ++n)
#pragma unroll
      for (int r = 0; r < 4; ++r) {
        const int qrow = qw0 + g * 4 + r;
        const int key = kt * 64 + n * 16 + c;
        float v = s[n][r] * 0.125f;
        if (key > qrow) v = -1e30f;
        p[n][r] = v;
        mx[r] = fmaxf(mx[r], v);
      }
#pragma unroll
    for (int r = 0; r < 4; ++r)
#pragma unroll
      for (int m = 1; m <= 8; m <<= 1) mx[r] = fmaxf(mx[r], __shfl_xor(mx[r], m));
    float al[4], rs[4];
#pragma unroll
    for (int r = 0; r < 4; ++r) {
      const float mn = fmaxf(mrun[r], mx[r]);
      al[r] = __expf(mrun[r] - mn);
      mrun[r] = mn;
      rs[r] = 0.f;
    }
#pragma unroll
    for (int n = 0; n < 4; ++n)
#pragma unroll
      for (int r = 0; r < 4; ++r) {
        const float e = __expf(p[n][r] - mrun[r]);
        p[n][r] = e;
        rs[r] += e;
      }
#pragma unroll
    for (int r = 0; r < 4; ++r) {
#pragma unroll
      for (int m = 1; m <= 8; m <<= 1) rs[r] += __shfl_xor(rs[r], m);
      lrun[r] = lrun[r] * al[r] + rs[r];
    }
#pragma unroll
    for (int n = 0; n < 4; ++n)
#pragma unroll
      for (int r = 0; r < 4; ++r) acc[n][r] *= al[r];
    __syncthreads();  // prior PV reads of lP complete
#pragma unroll
    for (int n = 0; n < 4; ++n)
#pragma unroll
      for (int r = 0; r < 4; ++r)
        lP[wv][(g * 4 + r) * 64 + n * 16 + c] = f2bf(p[n][r]);
    __syncthreads();  // P visible
    s16x8 pa0 = *(const s16x8*)&lP[wv][c * 64 + g * 8];
    s16x8 pa1 = *(const s16x8*)&lP[wv][c * 64 + 32 + g * 8];
#pragma unroll
    for (int n = 0; n < 4; ++n) {
      const size_t voff = ((size_t)(bh * 64 + n * 16 + c)) * 1024 + kt * 64 + g * 8;
      s16x8 v0 = *(const s16x8*)&Vt[voff];
      s16x8 v1 = *(const s16x8*)&Vt[voff + 32];
      acc[n] = __builtin_amdgcn_mfma_f32_16x16x32_bf16(pa0, v0, acc[n], 0, 0, 0);
      acc[n] = __builtin_amdgcn_mfma_f32_16x16x32_bf16(pa1, v1, acc[n], 0, 0, 0);
    }
  }
#pragma unroll
  for (int n = 0; n < 4; ++n)
#pragma unroll
    for (int r = 0; r < 4; ++r) {
      const size_t row = (size_t)(b * 1024 + qw0 + g * 4 + r);
      O[row * DM + h * 64 + n * 16 + c] = f2bf(acc[n][r] / lrun[r]);
    }
}

// ---------------- host ----------------
extern "C" void kernel_launch(void* const* d_in, const int* in_sizes, int n_in,
                              void* d_out, int out_size, void* d_ws, size_t ws_size,
                              hipStream_t stream) {
  const int* idx = (const int*)d_in[0];
  const float* wte = (const float*)d_in[1];
  const float* wpe = (const float*)d_in[2];
  const float* wq = (const float*)d_in[3];
  const float* wk = (const float*)d_in[4];
  const float* wv = (const float*)d_in[5];
  const float* wo = (const float*)d_in[6];
  const float* bo = (const float*)d_in[7];
  const float* ln1w = (const float*)d_in[8];
  const float* ln1b = (const float*)d_in[9];
  const float* ln2w = (const float*)d_in[10];
  const float* ln2b = (const float*)d_in[11];
  const float* w1 = (const float*)d_in[12];
  const float* b1 = (const float*)d_in[13];
  const float* w2 = (const float*)d_in[14];
  const float* b2 = (const float*)d_in[15];
  const float* lnfw = (const float*)d_in[16];
  const float* lnfb = (const float*)d_in[17];
  const float* wlm = (const float*)d_in[18];
  const float* blm = (const float*)d_in[19];
  float* out = (float*)d_out;

  char* ws = (char*)d_ws;
  size_t off = 0;
  auto alloc = [&](size_t bytes) -> void* {
    void* p = ws + off;
    off += (bytes + 255) & ~(size_t)255;
    return p;
  };
  // fused QKV weights: [L][3072 rows][1024 K] bf16
  unsigned short* wqkvT = (unsigned short*)alloc((size_t)NLAYER * 3072 * DM * 2);  // 48MB
  unsigned short* woT = (unsigned short*)alloc((size_t)NLAYER * DM * DM * 2);      // 16MB
  unsigned short* w1T = (unsigned short*)alloc((size_t)NLAYER * DM * DFF2 * 2);    // 64MB
  unsigned short* w2T = (unsigned short*)alloc((size_t)NLAYER * DM * DFF2 * 2);    // 64MB
  // wlmT aliases w1T+w2T (dead after the layer loop): 103MB <= 128MB
  unsigned short* wlmT = w1T;
  float* X = (float*)alloc((size_t)NTOK * DM * 4);                                 // 16MB
  unsigned short* Hb = (unsigned short*)alloc((size_t)NTOK * DM * 2);              // 8MB
  // union region 32MB: {QKVb 24MB + Ab 8MB} early, {P0 16MB + P1 16MB} at w2
  char* uni = (char*)alloc((size_t)32 * 1024 * 1024);
  unsigned short* QKVb = (unsigned short*)uni;
  unsigned short* Ab = (unsigned short*)(uni + (size_t)24 * 1024 * 1024);
  float* P0 = (float*)uni;
  float* P1 = (float*)(uni + (size_t)16 * 1024 * 1024);
  unsigned short* VtB = (unsigned short*)alloc((size_t)NTOK * DM * 2);             // 8MB
  unsigned short* Mid = (unsigned short*)alloc((size_t)NTOK * DFF2 * 2);           // 32MB

  // weight conversions (per-call; deterministic). QKV fused: rows [0,1024)=q,
  // [1024,2048)=k, [2048,3072)=v, per-layer stride 3072*1024.
  const size_t qkvStride = (size_t)3072 * DM;
  convT_k<<<dim3(16, 16, 8), 256, 0, stream>>>(wq, wqkvT, DM, DM, qkvStride);
  convT_k<<<dim3(16, 16, 8), 256, 0, stream>>>(wk, wqkvT + (size_t)1024 * DM, DM, DM, qkvStride);
  convT_k<<<dim3(16, 16, 8), 256, 0, stream>>>(wv, wqkvT + (size_t)2048 * DM, DM, DM, qkvStride);
  convT_k<<<dim3(16, 16, 8), 256, 0, stream>>>(wo, woT, DM, DM, (size_t)DM * DM);
  convT_k<<<dim3(64, 16, 8), 256, 0, stream>>>(w1, w1T, DM, DFF2, (size_t)DM * DFF2);
  convT_k<<<dim3(16, 64, 8), 256, 0, stream>>>(w2, w2T, DFF2, DM, (size_t)DM * DFF2);

  embed_k<<<dim3(NTOK), 256, 0, stream>>>(idx, wte, wpe, X);

  for (int i = 0; i < NLAYER; ++i) {
    const size_t wOff = (size_t)i * DM * DM;
    const size_t fOff = (size_t)i * DM * DFF2;
    ln_k<<<dim3(NTOK), 256, 0, stream>>>(X, ln1w + i * DM, ln1b + i * DM, Hb);
    // fused QKV: [4096,3072] = Hb @ wqkv^T
    gemm_k<<<dim3(24, 32), 256, 0, stream>>>(Hb, wqkvT + i * qkvStride, nullptr,
                                             nullptr, nullptr, QKVb, NTOK, 3072,
                                             DM, DM, 3072, 0);
    vtrans_k<<<dim3(16, 64), 256, 0, stream>>>(QKVb + 2048, VtB, 3072);
    attn_k<<<dim3(16, 64), 256, 0, stream>>>(QKVb, QKVb + 1024, VtB, Ab, 3072);
    gemm_k<<<dim3(8, 32), 256, 0, stream>>>(Ab, woT + wOff, bo + i * DM, X, X,
                                            nullptr, NTOK, DM, DM, DM, DM, 0);
    ln_k<<<dim3(NTOK), 256, 0, stream>>>(X, ln2w + i * DM, ln2b + i * DM, Hb);
    gemm_k<<<dim3(32, 32), 256, 0, stream>>>(Hb, w1T + fOff, b1 + i * DFF2,
                                             nullptr, nullptr, Mid, NTOK, DFF2,
                                             DM, DM, DFF2, 1);
    // w2: split-K=2 (z chunks of 2048), deterministic partials then reduce
    gemm_k<<<dim3(8, 32, 2), 256, 0, stream>>>(Mid, w2T + fOff, nullptr, nullptr,
                                               P0, nullptr, NTOK, DM, DFF2 / 2,
                                               DFF2, DM, 0);
    reduce2_k<<<dim3(NTOK), 256, 0, stream>>>(X, b2 + i * DM, P0, P1);
  }

  // LM head: convert wlm (aliases dead w1T/w2T region), final LN, big GEMM
  convT_k<<<dim3(786, 16, 1), 256, 0, stream>>>(wlm, wlmT, DM, NV, 0);
  ln_k<<<dim3(NTOK), 256, 0, stream>>>(X, lnfw, lnfb, Hb);
  gemm_k<<<dim3(393, 32), 256, 0, stream>>>(Hb, wlmT, blm, nullptr, out, nullptr,
                                            NTOK, NV, DM, DM, NV, 0);
}

// Round 3
// 3931.800 us; speedup vs baseline: 1.3031x; 1.1025x over previous
//
#include <hip/hip_runtime.h>
#include <cstdint>
#include <cstddef>

typedef __attribute__((ext_vector_type(4))) float f32x4;
typedef __attribute__((ext_vector_type(8))) short s16x8;
typedef __attribute__((ext_vector_type(4))) unsigned short u16x4;
typedef __attribute__((ext_vector_type(2))) unsigned short u16x2;

#define NLAYER 8
#define DM 1024
#define NTOK 4096
#define DFF2 4096
#define NV 50257
#define NVP 50304

__device__ __forceinline__ unsigned short f2bf(float f) {
  unsigned int u = __float_as_uint(f);
  u = u + 0x7fffu + ((u >> 16) & 1u);
  return (unsigned short)(u >> 16);
}

// CK-style generic->AS1/AS3 conversion for global_load_lds (width 16B).
__device__ __forceinline__ void gload_lds16(const void* gp, void* lp) {
  const __attribute__((address_space(1))) unsigned int* g =
      reinterpret_cast<const __attribute__((address_space(1))) unsigned int*>(
          reinterpret_cast<uintptr_t>(gp));
  __attribute__((address_space(3))) unsigned int* l =
      reinterpret_cast<__attribute__((address_space(3))) unsigned int*>(
          (unsigned int)(uintptr_t)lp);
  __builtin_amdgcn_global_load_lds(g, l, 16, 0, 0);
}

// ---------------- weight convert + transpose: out[n][k] = bf16(in[k][n]) ----
__global__ void __launch_bounds__(256) convT_k(const float* __restrict__ in,
                                               unsigned short* __restrict__ out,
                                               int K, int N, size_t zStride) {
  __shared__ float tile[64][65];
  const int n0 = blockIdx.x * 64, k0 = blockIdx.y * 64;
  const float* inp = in + (size_t)blockIdx.z * K * N;
  unsigned short* outp = out + (size_t)blockIdx.z * zStride;
  const int tid = threadIdx.x;
#pragma unroll
  for (int p = 0; p < 16; ++p) {
    const int r = p * 4 + (tid >> 6);
    const int cc = tid & 63;
    const int gn = n0 + cc;
    tile[r][cc] = (gn < N) ? inp[(size_t)(k0 + r) * N + gn] : 0.f;
  }
  __syncthreads();
#pragma unroll
  for (int p = 0; p < 8; ++p) {
    const int lin = p * 256 + tid;
    const int rn = lin >> 5;
    const int c2 = (lin & 31) * 2;
    u16x2 o;
    o[0] = f2bf(tile[c2][rn]);
    o[1] = f2bf(tile[c2 + 1][rn]);
    *(u16x2*)&outp[(size_t)(n0 + rn) * K + k0 + c2] = o;
  }
}

// ---------------- embedding: x = wte[idx] + wpe[t] ----------------
__global__ void __launch_bounds__(256) embed_k(const int* __restrict__ idx,
                                               const float* __restrict__ wte,
                                               const float* __restrict__ wpe,
                                               float* __restrict__ X) {
  const int tok = blockIdx.x;
  const int t = tok & 1023;
  const int id = idx[tok];
  const int c = threadIdx.x * 4;
  f32x4 a = *(const f32x4*)&wte[(size_t)id * DM + c];
  f32x4 p = *(const f32x4*)&wpe[(size_t)t * DM + c];
  a = a + p;
  *(f32x4*)&X[(size_t)tok * DM + c] = a;
}

// ---------------- LayerNorm: f32 in -> bf16 out ----------------
__global__ void __launch_bounds__(256) ln_k(const float* __restrict__ X,
                                            const float* __restrict__ W,
                                            const float* __restrict__ Bp,
                                            unsigned short* __restrict__ O) {
  const int row = blockIdx.x, tid = threadIdx.x;
  const size_t base = (size_t)row * DM;
  f32x4 v = *(const f32x4*)&X[base + tid * 4];
  float s = v[0] + v[1] + v[2] + v[3];
  float q = v[0] * v[0] + v[1] * v[1] + v[2] * v[2] + v[3] * v[3];
#pragma unroll
  for (int m = 1; m < 64; m <<= 1) {
    s += __shfl_xor(s, m);
    q += __shfl_xor(q, m);
  }
  __shared__ float ps[4], pq[4];
  const int wv = tid >> 6;
  if ((tid & 63) == 0) { ps[wv] = s; pq[wv] = q; }
  __syncthreads();
  s = ps[0] + ps[1] + ps[2] + ps[3];
  q = pq[0] + pq[1] + pq[2] + pq[3];
  const float mu = s * (1.f / DM);
  const float var = q * (1.f / DM) - mu * mu;
  const float rstd = rsqrtf(var + 1e-5f);
  f32x4 w = *(const f32x4*)&W[tid * 4];
  f32x4 bb = *(const f32x4*)&Bp[tid * 4];
  u16x4 o;
#pragma unroll
  for (int j = 0; j < 4; ++j) o[j] = f2bf((v[j] - mu) * rstd * w[j] + bb[j]);
  *(u16x4*)&O[base + tid * 4] = o;
}

// ---------------- residual reduce: X += bias + P0 + P1 ----------------
__global__ void __launch_bounds__(256) reduce2_k(float* __restrict__ X,
                                                 const float* __restrict__ bias,
                                                 const float* __restrict__ P0,
                                                 const float* __restrict__ P1) {
  const size_t i = (size_t)blockIdx.x * DM + threadIdx.x * 4;
  f32x4 x = *(f32x4*)&X[i];
  f32x4 b = *(const f32x4*)&bias[threadIdx.x * 4];
  f32x4 a = *(const f32x4*)&P0[i];
  f32x4 c = *(const f32x4*)&P1[i];
  x = x + b + a + c;
  *(f32x4*)&X[i] = x;
}

// ---------------- GEMM: C[M,N] = A[M,K](bf16) x Bt[N,K]^T(bf16) + epilogue --
// 128x128 tile, BK=64, 4 waves, 16x16x32 bf16 MFMA (m97 structure, natural
// block order). LDS [128][64] with XOR swizzle: element k-offset within a row
// is XOR'd with (row&7)*8. Write side achieves this via pre-swizzled GLOBAL
// source + linear global_load_lds dest (m173/m201 both-sides pattern); read
// side applies the same XOR -> conflict-free b128 reads (8 lanes/quad, min).
// blockIdx.z = K-split chunk (partials to outF + z*M*ldc).
__global__ void __launch_bounds__(256) gemm_k(
    const unsigned short* __restrict__ A, const unsigned short* __restrict__ Bt,
    const float* __restrict__ bias, const float* __restrict__ resid,
    float* __restrict__ outF, unsigned short* __restrict__ outB,
    int M, int N, int K, int lda, int ldc, int relu) {
  __shared__ __align__(16) unsigned short lA[128 * 64];
  __shared__ __align__(16) unsigned short lB[128 * 64];
  const int tid = threadIdx.x;
  const int wv = tid >> 6, lane = tid & 63;
  const int row0 = blockIdx.y * 128, col0 = blockIdx.x * 128;
  const int wr = wv >> 1, wc = wv & 1;

  const int z = blockIdx.z;
  A += (size_t)z * K;
  Bt += (size_t)z * K;
  if (gridDim.z > 1) outF += (size_t)z * M * ldc;

  f32x4 acc[4][4] = {};

  // staging: thread t covers LDS row sRow=t>>3 (per 32-row issue chunk),
  // 16B slot (t&7); global source column pre-swizzled by (sRow&7)*8.
  const int sRow = tid >> 3;                                  // 0..31
  const int sColSw = ((tid & 7) * 8) ^ ((sRow & 7) * 8);      // elements, [0,64)
  const unsigned short* gA = A + (size_t)(row0 + sRow) * lda + sColSw;
  const unsigned short* gB = Bt + (size_t)(col0 + sRow) * lda + sColSw;
  unsigned short* lAd = lA + tid * 8;  // linear: wave base + lane*16B
  unsigned short* lBd = lB + tid * 8;
  const size_t step32 = (size_t)32 * lda;

  // ds_read: logical k-elem (kk*32 + (lane>>4)*8) XOR'd with (row&7)*8,
  // row&7 == lane&7 (m*16 and wr*64 are 0 mod 8).
  const int rbase = lane & 15;
  const int kHi = (lane >> 4) * 8;
  const int kSw = (lane & 7) * 8;

  for (int kt = 0; kt < K; kt += 64) {
#pragma unroll
    for (int i = 0; i < 4; ++i) {
      gload_lds16(gA + kt + i * step32, lAd + i * 2048);
      gload_lds16(gB + kt + i * step32, lBd + i * 2048);
    }
    __syncthreads();  // drains vmcnt -> LDS tiles ready
    s16x8 af[2][4], bfr[2][4];
#pragma unroll
    for (int kk = 0; kk < 2; ++kk) {
      const int kph = (kk * 32 + kHi) ^ kSw;
#pragma unroll
      for (int m = 0; m < 4; ++m)
        af[kk][m] = *(const s16x8*)&lA[(wr * 64 + m * 16 + rbase) * 64 + kph];
#pragma unroll
      for (int n = 0; n < 4; ++n)
        bfr[kk][n] = *(const s16x8*)&lB[(wc * 64 + n * 16 + rbase) * 64 + kph];
    }
#pragma unroll
    for (int kk = 0; kk < 2; ++kk)
#pragma unroll
      for (int m = 0; m < 4; ++m)
#pragma unroll
        for (int n = 0; n < 4; ++n)
          acc[m][n] = __builtin_amdgcn_mfma_f32_16x16x32_bf16(
              af[kk][m], bfr[kk][n], acc[m][n], 0, 0, 0);
    __syncthreads();  // all reads done before next stage overwrites
  }

  const int baseRow = row0 + wr * 64 + ((lane >> 4) * 4);
  const int baseCol = col0 + wc * 64 + (lane & 15);
#pragma unroll
  for (int m = 0; m < 4; ++m) {
#pragma unroll
    for (int n = 0; n < 4; ++n) {
      const int colc = baseCol + n * 16;
      if (colc < N) {
        const float bv = bias ? bias[colc] : 0.f;
#pragma unroll
        for (int r = 0; r < 4; ++r) {
          const int rowc = baseRow + m * 16 + r;
          float v = acc[m][n][r] + bv;
          if (resid) v += resid[(size_t)rowc * ldc + colc];
          if (relu) v = fmaxf(v, 0.f);
          if (outF) outF[(size_t)rowc * ldc + colc] = v;
          if (outB) outB[(size_t)rowc * ldc + colc] = f2bf(v);
        }
      }
    }
  }
}

// ---------------- V transpose: V[B*T, ldv] -> Vt[bh][hs][t] ----------------
__global__ void __launch_bounds__(256) vtrans_k(const unsigned short* __restrict__ V,
                                                unsigned short* __restrict__ Vt,
                                                int ldv) {
  __shared__ unsigned short tile[64][72];
  const int tt = blockIdx.x, bh = blockIdx.y;
  const int b = bh >> 4, h = bh & 15;
  const int tid = threadIdx.x;
#pragma unroll
  for (int p = 0; p < 2; ++p) {
    const int r = (tid >> 3) + p * 32;
    const int c8 = (tid & 7) * 8;
    s16x8 v = *(const s16x8*)&V[((size_t)(b * 1024 + tt * 64 + r)) * ldv + h * 64 + c8];
#pragma unroll
    for (int j = 0; j < 8; ++j) tile[r][c8 + j] = (unsigned short)v[j];
  }
  __syncthreads();
#pragma unroll
  for (int p = 0; p < 2; ++p) {
    const int hs = (tid >> 3) + p * 32;
    const int t8 = (tid & 7) * 8;
    s16x8 o;
#pragma unroll
    for (int j = 0; j < 8; ++j) o[j] = (short)tile[t8 + j][hs];
    *(s16x8*)&Vt[((size_t)(bh * 64 + hs)) * 1024 + tt * 64 + t8] = o;
  }
}

// ---------------- fused causal attention (flash-style) ----------------
// grid: (qtile 16, bh 64); block 256 = 4 waves; each wave owns 16 q-rows.
__global__ void __launch_bounds__(256) attn_k(const unsigned short* __restrict__ Q,
                                              const unsigned short* __restrict__ Kb,
                                              const unsigned short* __restrict__ Vt,
                                              unsigned short* __restrict__ O,
                                              int ldq) {
  const int qt = blockIdx.x;
  const int bh = blockIdx.y;
  const int b = bh >> 4, h = bh & 15;
  const int tid = threadIdx.x, wv = tid >> 6, lane = tid & 63;
  const int g = lane >> 4, c = lane & 15;
  __shared__ __align__(16) unsigned short lP[4][16 * 64];
  const int qw0 = qt * 64 + wv * 16;
  s16x8 qf0, qf1;
  {
    const size_t qoff = ((size_t)(b * 1024 + qw0 + c)) * ldq + h * 64 + g * 8;
    qf0 = *(const s16x8*)&Q[qoff];
    qf1 = *(const s16x8*)&Q[qoff + 32];
  }
  f32x4 acc[4] = {};
  float mrun[4], lrun[4];
#pragma unroll
  for (int r = 0; r < 4; ++r) { mrun[r] = -1e30f; lrun[r] = 0.f; }

  for (int kt = 0; kt <= qt; ++kt) {
    f32x4 s[4] = {};
#pragma unroll
    for (int n = 0; n < 4; ++n) {
      const size_t koff = ((size_t)(b * 1024 + kt * 64 + n * 16 + c)) * ldq + h * 64 + g * 8;
      s16x8 k0 = *(const s16x8*)&Kb[koff];
      s16x8 k1 = *(const s16x8*)&Kb[koff + 32];
      s[n] = __builtin_amdgcn_mfma_f32_16x16x32_bf16(qf0, k0, s[n], 0, 0, 0);
      s[n] = __builtin_amdgcn_mfma_f32_16x16x32_bf16(qf1, k1, s[n], 0, 0, 0);
    }
    float p[4][4], mx[4] = {-1e30f, -1e30f, -1e30f, -1e30f};
#pragma unroll
    for (int n = 0; n < 4; ++n)
#pragma unroll
      for (int r = 0; r < 4; ++r) {
        const int qrow = qw0 + g * 4 + r;
        const int key = kt * 64 + n * 16 + c;
        float v = s[n][r] * 0.125f;
        if (key > qrow) v = -1e30f;
        p[n][r] = v;
        mx[r] = fmaxf(mx[r], v);
      }
#pragma unroll
    for (int r = 0; r < 4; ++r)
#pragma unroll
      for (int m = 1; m <= 8; m <<= 1) mx[r] = fmaxf(mx[r], __shfl_xor(mx[r], m));
    float al[4], rs[4];
#pragma unroll
    for (int r = 0; r < 4; ++r) {
      const float mn = fmaxf(mrun[r], mx[r]);
      al[r] = __expf(mrun[r] - mn);
      mrun[r] = mn;
      rs[r] = 0.f;
    }
#pragma unroll
    for (int n = 0; n < 4; ++n)
#pragma unroll
      for (int r = 0; r < 4; ++r) {
        const float e = __expf(p[n][r] - mrun[r]);
        p[n][r] = e;
        rs[r] += e;
      }
#pragma unroll
    for (int r = 0; r < 4; ++r) {
#pragma unroll
      for (int m = 1; m <= 8; m <<= 1) rs[r] += __shfl_xor(rs[r], m);
      lrun[r] = lrun[r] * al[r] + rs[r];
    }
#pragma unroll
    for (int n = 0; n < 4; ++n)
#pragma unroll
      for (int r = 0; r < 4; ++r) acc[n][r] *= al[r];
    __syncthreads();  // prior PV reads of lP complete
#pragma unroll
    for (int n = 0; n < 4; ++n)
#pragma unroll
      for (int r = 0; r < 4; ++r)
        lP[wv][(g * 4 + r) * 64 + n * 16 + c] = f2bf(p[n][r]);
    __syncthreads();  // P visible
    s16x8 pa0 = *(const s16x8*)&lP[wv][c * 64 + g * 8];
    s16x8 pa1 = *(const s16x8*)&lP[wv][c * 64 + 32 + g * 8];
#pragma unroll
    for (int n = 0; n < 4; ++n) {
      const size_t voff = ((size_t)(bh * 64 + n * 16 + c)) * 1024 + kt * 64 + g * 8;
      s16x8 v0 = *(const s16x8*)&Vt[voff];
      s16x8 v1 = *(const s16x8*)&Vt[voff + 32];
      acc[n] = __builtin_amdgcn_mfma_f32_16x16x32_bf16(pa0, v0, acc[n], 0, 0, 0);
      acc[n] = __builtin_amdgcn_mfma_f32_16x16x32_bf16(pa1, v1, acc[n], 0, 0, 0);
    }
  }
#pragma unroll
  for (int n = 0; n < 4; ++n)
#pragma unroll
    for (int r = 0; r < 4; ++r) {
      const size_t row = (size_t)(b * 1024 + qw0 + g * 4 + r);
      O[row * DM + h * 64 + n * 16 + c] = f2bf(acc[n][r] / lrun[r]);
    }
}

// ---------------- host ----------------
extern "C" void kernel_launch(void* const* d_in, const int* in_sizes, int n_in,
                              void* d_out, int out_size, void* d_ws, size_t ws_size,
                              hipStream_t stream) {
  const int* idx = (const int*)d_in[0];
  const float* wte = (const float*)d_in[1];
  const float* wpe = (const float*)d_in[2];
  const float* wq = (const float*)d_in[3];
  const float* wk = (const float*)d_in[4];
  const float* wv = (const float*)d_in[5];
  const float* wo = (const float*)d_in[6];
  const float* bo = (const float*)d_in[7];
  const float* ln1w = (const float*)d_in[8];
  const float* ln1b = (const float*)d_in[9];
  const float* ln2w = (const float*)d_in[10];
  const float* ln2b = (const float*)d_in[11];
  const float* w1 = (const float*)d_in[12];
  const float* b1 = (const float*)d_in[13];
  const float* w2 = (const float*)d_in[14];
  const float* b2 = (const float*)d_in[15];
  const float* lnfw = (const float*)d_in[16];
  const float* lnfb = (const float*)d_in[17];
  const float* wlm = (const float*)d_in[18];
  const float* blm = (const float*)d_in[19];
  float* out = (float*)d_out;

  char* ws = (char*)d_ws;
  size_t off = 0;
  auto alloc = [&](size_t bytes) -> void* {
    void* p = ws + off;
    off += (bytes + 255) & ~(size_t)255;
    return p;
  };
  // fused QKV weights: [L][3072 rows][1024 K] bf16
  unsigned short* wqkvT = (unsigned short*)alloc((size_t)NLAYER * 3072 * DM * 2);  // 48MB
  unsigned short* woT = (unsigned short*)alloc((size_t)NLAYER * DM * DM * 2);      // 16MB
  unsigned short* w1T = (unsigned short*)alloc((size_t)NLAYER * DM * DFF2 * 2);    // 64MB
  unsigned short* w2T = (unsigned short*)alloc((size_t)NLAYER * DM * DFF2 * 2);    // 64MB
  // wlmT aliases w1T+w2T (dead after the layer loop): 103MB <= 128MB
  unsigned short* wlmT = w1T;
  float* X = (float*)alloc((size_t)NTOK * DM * 4);                                 // 16MB
  unsigned short* Hb = (unsigned short*)alloc((size_t)NTOK * DM * 2);              // 8MB
  // union region 32MB: {QKVb 24MB + Ab 8MB} early, {P0 16MB + P1 16MB} at w2
  char* uni = (char*)alloc((size_t)32 * 1024 * 1024);
  unsigned short* QKVb = (unsigned short*)uni;
  unsigned short* Ab = (unsigned short*)(uni + (size_t)24 * 1024 * 1024);
  float* P0 = (float*)uni;
  float* P1 = (float*)(uni + (size_t)16 * 1024 * 1024);
  unsigned short* VtB = (unsigned short*)alloc((size_t)NTOK * DM * 2);             // 8MB
  // Mid: bf16 [4096,4096] between w1/w2; also reused (float) as wo's split-K
  // partials (dead in that window)
  unsigned short* Mid = (unsigned short*)alloc((size_t)NTOK * DFF2 * 2);           // 32MB
  float* MidF = (float*)Mid;

  // weight conversions (per-call; deterministic). QKV fused: rows [0,1024)=q,
  // [1024,2048)=k, [2048,3072)=v, per-layer stride 3072*1024.
  const size_t qkvStride = (size_t)3072 * DM;
  convT_k<<<dim3(16, 16, 8), 256, 0, stream>>>(wq, wqkvT, DM, DM, qkvStride);
  convT_k<<<dim3(16, 16, 8), 256, 0, stream>>>(wk, wqkvT + (size_t)1024 * DM, DM, DM, qkvStride);
  convT_k<<<dim3(16, 16, 8), 256, 0, stream>>>(wv, wqkvT + (size_t)2048 * DM, DM, DM, qkvStride);
  convT_k<<<dim3(16, 16, 8), 256, 0, stream>>>(wo, woT, DM, DM, (size_t)DM * DM);
  convT_k<<<dim3(64, 16, 8), 256, 0, stream>>>(w1, w1T, DM, DFF2, (size_t)DM * DFF2);
  convT_k<<<dim3(16, 64, 8), 256, 0, stream>>>(w2, w2T, DFF2, DM, (size_t)DM * DFF2);

  embed_k<<<dim3(NTOK), 256, 0, stream>>>(idx, wte, wpe, X);

  for (int i = 0; i < NLAYER; ++i) {
    const size_t wOff = (size_t)i * DM * DM;
    const size_t fOff = (size_t)i * DM * DFF2;
    ln_k<<<dim3(NTOK), 256, 0, stream>>>(X, ln1w + i * DM, ln1b + i * DM, Hb);
    // fused QKV: [4096,3072] = Hb @ wqkv^T
    gemm_k<<<dim3(24, 32), 256, 0, stream>>>(Hb, wqkvT + i * qkvStride, nullptr,
                                             nullptr, nullptr, QKVb, NTOK, 3072,
                                             DM, DM, 3072, 0);
    vtrans_k<<<dim3(16, 64), 256, 0, stream>>>(QKVb + 2048, VtB, 3072);
    attn_k<<<dim3(16, 64), 256, 0, stream>>>(QKVb, QKVb + 1024, VtB, Ab, 3072);
    // wo: split-K=2 (z chunks of 512), partials into MidF (dead here)
    gemm_k<<<dim3(8, 32, 2), 256, 0, stream>>>(Ab, woT + wOff, nullptr, nullptr,
                                               MidF, nullptr, NTOK, DM, DM / 2,
                                               DM, DM, 0);
    reduce2_k<<<dim3(NTOK), 256, 0, stream>>>(X, bo + i * DM, MidF,
                                              MidF + (size_t)NTOK * DM);
    ln_k<<<dim3(NTOK), 256, 0, stream>>>(X, ln2w + i * DM, ln2b + i * DM, Hb);
    gemm_k<<<dim3(32, 32), 256, 0, stream>>>(Hb, w1T + fOff, b1 + i * DFF2,
                                             nullptr, nullptr, Mid, NTOK, DFF2,
                                             DM, DM, DFF2, 1);
    // w2: split-K=2 (z chunks of 2048), partials P0/P1 (union region, free)
    gemm_k<<<dim3(8, 32, 2), 256, 0, stream>>>(Mid, w2T + fOff, nullptr, nullptr,
                                               P0, nullptr, NTOK, DM, DFF2 / 2,
                                               DFF2, DM, 0);
    reduce2_k<<<dim3(NTOK), 256, 0, stream>>>(X, b2 + i * DM, P0, P1);
  }

  // LM head: convert wlm (aliases dead w1T/w2T region), final LN, big GEMM
  convT_k<<<dim3(786, 16, 1), 256, 0, stream>>>(wlm, wlmT, DM, NV, 0);
  ln_k<<<dim3(NTOK), 256, 0, stream>>>(X, lnfw, lnfb, Hb);
  gemm_k<<<dim3(393, 32), 256, 0, stream>>>(Hb, wlmT, blm, nullptr, out, nullptr,
                                            NTOK, NV, DM, DM, NV, 0);
}

// Round 4
// 3413.696 us; speedup vs baseline: 1.5009x; 1.1518x over previous
//
#include <hip/hip_runtime.h>
#include <cstdint>
#include <cstddef>

typedef __attribute__((ext_vector_type(4))) float f32x4;
typedef __attribute__((ext_vector_type(8))) short s16x8;
typedef __attribute__((ext_vector_type(4))) unsigned short u16x4;
typedef __attribute__((ext_vector_type(2))) unsigned short u16x2;

#define NLAYER 8
#define DM 1024
#define NTOK 4096
#define DFF2 4096
#define NV 50257
#define NVPAD 50432  // 197*256, for 256-wide LM tiles

__device__ __forceinline__ unsigned short f2bf(float f) {
  unsigned int u = __float_as_uint(f);
  u = u + 0x7fffu + ((u >> 16) & 1u);
  return (unsigned short)(u >> 16);
}

// CK-style generic->AS1/AS3 conversion for global_load_lds (width 16B).
__device__ __forceinline__ void gload_lds16(const void* gp, void* lp) {
  const __attribute__((address_space(1))) unsigned int* g =
      reinterpret_cast<const __attribute__((address_space(1))) unsigned int*>(
          reinterpret_cast<uintptr_t>(gp));
  __attribute__((address_space(3))) unsigned int* l =
      reinterpret_cast<__attribute__((address_space(3))) unsigned int*>(
          (unsigned int)(uintptr_t)lp);
  __builtin_amdgcn_global_load_lds(g, l, 16, 0, 0);
}

// ---------------- weight convert + transpose: out[n][k] = bf16(in[k][n]) ----
__global__ void __launch_bounds__(256) convT_k(const float* __restrict__ in,
                                               unsigned short* __restrict__ out,
                                               int K, int N, size_t zStride) {
  __shared__ float tile[64][65];
  const int n0 = blockIdx.x * 64, k0 = blockIdx.y * 64;
  const float* inp = in + (size_t)blockIdx.z * K * N;
  unsigned short* outp = out + (size_t)blockIdx.z * zStride;
  const int tid = threadIdx.x;
#pragma unroll
  for (int p = 0; p < 16; ++p) {
    const int r = p * 4 + (tid >> 6);
    const int cc = tid & 63;
    const int gn = n0 + cc;
    tile[r][cc] = (gn < N) ? inp[(size_t)(k0 + r) * N + gn] : 0.f;
  }
  __syncthreads();
#pragma unroll
  for (int p = 0; p < 8; ++p) {
    const int lin = p * 256 + tid;
    const int rn = lin >> 5;
    const int c2 = (lin & 31) * 2;
    u16x2 o;
    o[0] = f2bf(tile[c2][rn]);
    o[1] = f2bf(tile[c2 + 1][rn]);
    *(u16x2*)&outp[(size_t)(n0 + rn) * K + k0 + c2] = o;
  }
}

// ---------------- embedding: x = wte[idx] + wpe[t] ----------------
__global__ void __launch_bounds__(256) embed_k(const int* __restrict__ idx,
                                               const float* __restrict__ wte,
                                               const float* __restrict__ wpe,
                                               float* __restrict__ X) {
  const int tok = blockIdx.x;
  const int t = tok & 1023;
  const int id = idx[tok];
  const int c = threadIdx.x * 4;
  f32x4 a = *(const f32x4*)&wte[(size_t)id * DM + c];
  f32x4 p = *(const f32x4*)&wpe[(size_t)t * DM + c];
  a = a + p;
  *(f32x4*)&X[(size_t)tok * DM + c] = a;
}

// ---------------- LayerNorm: f32 in -> bf16 out ----------------
__global__ void __launch_bounds__(256) ln_k(const float* __restrict__ X,
                                            const float* __restrict__ W,
                                            const float* __restrict__ Bp,
                                            unsigned short* __restrict__ O) {
  const int row = blockIdx.x, tid = threadIdx.x;
  const size_t base = (size_t)row * DM;
  f32x4 v = *(const f32x4*)&X[base + tid * 4];
  float s = v[0] + v[1] + v[2] + v[3];
  float q = v[0] * v[0] + v[1] * v[1] + v[2] * v[2] + v[3] * v[3];
#pragma unroll
  for (int m = 1; m < 64; m <<= 1) {
    s += __shfl_xor(s, m);
    q += __shfl_xor(q, m);
  }
  __shared__ float ps[4], pq[4];
  const int wv = tid >> 6;
  if ((tid & 63) == 0) { ps[wv] = s; pq[wv] = q; }
  __syncthreads();
  s = ps[0] + ps[1] + ps[2] + ps[3];
  q = pq[0] + pq[1] + pq[2] + pq[3];
  const float mu = s * (1.f / DM);
  const float var = q * (1.f / DM) - mu * mu;
  const float rstd = rsqrtf(var + 1e-5f);
  f32x4 w = *(const f32x4*)&W[tid * 4];
  f32x4 bb = *(const f32x4*)&Bp[tid * 4];
  u16x4 o;
#pragma unroll
  for (int j = 0; j < 4; ++j) o[j] = f2bf((v[j] - mu) * rstd * w[j] + bb[j]);
  *(u16x4*)&O[base + tid * 4] = o;
}

// -------- fused: X += bias + P0 + P1; then LN(X) -> bf16 O --------
__global__ void __launch_bounds__(256) reduce2ln_k(
    float* __restrict__ X, const float* __restrict__ bias,
    const float* __restrict__ P0, const float* __restrict__ P1,
    const float* __restrict__ W, const float* __restrict__ Bp,
    unsigned short* __restrict__ O) {
  const int row = blockIdx.x, tid = threadIdx.x;
  const size_t base = (size_t)row * DM;
  const size_t i = base + tid * 4;
  f32x4 v = *(f32x4*)&X[i];
  {
    f32x4 b = *(const f32x4*)&bias[tid * 4];
    f32x4 a = *(const f32x4*)&P0[i];
    f32x4 c = *(const f32x4*)&P1[i];
    v = v + b + a + c;
    *(f32x4*)&X[i] = v;
  }
  float s = v[0] + v[1] + v[2] + v[3];
  float q = v[0] * v[0] + v[1] * v[1] + v[2] * v[2] + v[3] * v[3];
#pragma unroll
  for (int m = 1; m < 64; m <<= 1) {
    s += __shfl_xor(s, m);
    q += __shfl_xor(q, m);
  }
  __shared__ float ps[4], pq[4];
  const int wv = tid >> 6;
  if ((tid & 63) == 0) { ps[wv] = s; pq[wv] = q; }
  __syncthreads();
  s = ps[0] + ps[1] + ps[2] + ps[3];
  q = pq[0] + pq[1] + pq[2] + pq[3];
  const float mu = s * (1.f / DM);
  const float var = q * (1.f / DM) - mu * mu;
  const float rstd = rsqrtf(var + 1e-5f);
  f32x4 w = *(const f32x4*)&W[tid * 4];
  f32x4 bb = *(const f32x4*)&Bp[tid * 4];
  u16x4 o;
#pragma unroll
  for (int j = 0; j < 4; ++j) o[j] = f2bf((v[j] - mu) * rstd * w[j] + bb[j]);
  *(u16x4*)&O[base + tid * 4] = o;
}

// ---------------- GEMM 128x128 (m97 structure, BK=64, XOR-swizzled LDS) ----
// Optional fused V-transpose epilogue: cols >= 2048 go to vt[bh][hs][t].
__global__ void __launch_bounds__(256) gemm_k(
    const unsigned short* __restrict__ A, const unsigned short* __restrict__ Bt,
    const float* __restrict__ bias, float* __restrict__ outF,
    unsigned short* __restrict__ outB, unsigned short* __restrict__ vt,
    int M, int N, int K, int lda, int ldc) {
  __shared__ __align__(16) unsigned short lA[128 * 64];
  __shared__ __align__(16) unsigned short lB[128 * 64];
  const int tid = threadIdx.x;
  const int wv = tid >> 6, lane = tid & 63;
  const int row0 = blockIdx.y * 128, col0 = blockIdx.x * 128;
  const int wr = wv >> 1, wc = wv & 1;

  const int z = blockIdx.z;
  A += (size_t)z * K;
  Bt += (size_t)z * K;
  if (gridDim.z > 1) outF += (size_t)z * M * ldc;

  f32x4 acc[4][4] = {};

  const int sRow = tid >> 3;                              // 0..31
  const int sColSw = ((tid & 7) * 8) ^ ((sRow & 7) * 8);  // elements, [0,64)
  const unsigned short* gA = A + (size_t)(row0 + sRow) * lda + sColSw;
  const unsigned short* gB = Bt + (size_t)(col0 + sRow) * lda + sColSw;
  unsigned short* lAd = lA + tid * 8;
  unsigned short* lBd = lB + tid * 8;
  const size_t step32 = (size_t)32 * lda;

  const int rbase = lane & 15;
  const int kHi = (lane >> 4) * 8;
  const int kSw = (lane & 7) * 8;

  for (int kt = 0; kt < K; kt += 64) {
#pragma unroll
    for (int i = 0; i < 4; ++i) {
      gload_lds16(gA + kt + i * step32, lAd + i * 2048);
      gload_lds16(gB + kt + i * step32, lBd + i * 2048);
    }
    __syncthreads();
    s16x8 af[2][4], bfr[2][4];
#pragma unroll
    for (int kk = 0; kk < 2; ++kk) {
      const int kph = (kk * 32 + kHi) ^ kSw;
#pragma unroll
      for (int m = 0; m < 4; ++m)
        af[kk][m] = *(const s16x8*)&lA[(wr * 64 + m * 16 + rbase) * 64 + kph];
#pragma unroll
      for (int n = 0; n < 4; ++n)
        bfr[kk][n] = *(const s16x8*)&lB[(wc * 64 + n * 16 + rbase) * 64 + kph];
    }
#pragma unroll
    for (int kk = 0; kk < 2; ++kk)
#pragma unroll
      for (int m = 0; m < 4; ++m)
#pragma unroll
        for (int n = 0; n < 4; ++n)
          acc[m][n] = __builtin_amdgcn_mfma_f32_16x16x32_bf16(
              af[kk][m], bfr[kk][n], acc[m][n], 0, 0, 0);
    __syncthreads();
  }

  const int baseRow = row0 + wr * 64 + ((lane >> 4) * 4);
  const int baseCol = col0 + wc * 64 + (lane & 15);
#pragma unroll
  for (int m = 0; m < 4; ++m) {
#pragma unroll
    for (int n = 0; n < 4; ++n) {
      const int colc = baseCol + n * 16;
      if (colc < N) {
        const int rowc0 = baseRow + m * 16;
        if (vt && colc >= 2048) {
          // fused V-transpose: Vt[(b*16+h)*64+hs][t], 4 consecutive t per lane
          const int f = colc - 2048;
          const int b = rowc0 >> 10, t0 = rowc0 & 1023;
          u16x4 o;
#pragma unroll
          for (int r = 0; r < 4; ++r) o[r] = f2bf(acc[m][n][r]);
          *(u16x4*)&vt[((size_t)((b << 4) + (f >> 6)) * 64 + (f & 63)) * 1024 + t0] = o;
        } else {
          const float bv = bias ? bias[colc] : 0.f;
#pragma unroll
          for (int r = 0; r < 4; ++r) {
            float v = acc[m][n][r] + bv;
            if (outF) outF[(size_t)(rowc0 + r) * ldc + colc] = v;
            if (outB) outB[(size_t)(rowc0 + r) * ldc + colc] = f2bf(v);
          }
        }
      }
    }
  }
}

// ------- GEMM 256x256, 8 waves, BK=64, dbuf LDS, prefetch-before-compute ----
// T3-min structure: issue next-tile global_load_lds first, then 4 quadrant
// phases of {ds_read frags, setprio(1), 16 MFMA, setprio(0)} on current tile,
// then one __syncthreads (its vmcnt(0)+lgkmcnt(0) drain = the depth-1 wait).
// XOR swizzle identical to gemm_k (proven 0-conflict round 3).
__global__ void __launch_bounds__(512, 2) gemm256_k(
    const unsigned short* __restrict__ A, const unsigned short* __restrict__ Bt,
    const float* __restrict__ bias, float* __restrict__ outF,
    unsigned short* __restrict__ outB, int M, int N, int K, int lda, int ldc,
    int relu) {
  __shared__ __align__(16) unsigned short lA[2][256 * 64];
  __shared__ __align__(16) unsigned short lB[2][256 * 64];
  const int tid = threadIdx.x;  // 0..511
  const int wv = tid >> 6, lane = tid & 63;
  const int row0 = blockIdx.y * 256, col0 = blockIdx.x * 256;
  const int wr = wv >> 2, wc = wv & 3;  // 2x4 wave grid; wave tile 128x64

  f32x4 acc[8][4] = {};

  const int sRow = tid >> 3;                              // 0..63
  const int sColSw = ((tid & 7) * 8) ^ ((sRow & 7) * 8);  // swizzled source col
  const unsigned short* gA = A + (size_t)(row0 + sRow) * lda + sColSw;
  const unsigned short* gB = Bt + (size_t)(col0 + sRow) * lda + sColSw;
  const size_t step64 = (size_t)64 * lda;
  const int ldsBase = wv * 512;  // per-wave uniform elem base; HW adds lane*16B

  const int rbase = lane & 15;
  const int g8 = (lane >> 4) * 8;
  const int kSw = (lane & 7) * 8;

  const int nt = K >> 6;
  // prologue: stage tile 0 into buf 0
#pragma unroll
  for (int i = 0; i < 4; ++i) {
    gload_lds16(gA + i * step64, &lA[0][i * 4096 + ldsBase]);
    gload_lds16(gB + i * step64, &lB[0][i * 4096 + ldsBase]);
  }
  for (int t = 0; t < nt; ++t) {
    const int cur = t & 1, nxt = cur ^ 1;
    const int ktn = (t + 1) << 6;
    __syncthreads();  // tile t landed; prior reads of buf nxt complete
    const unsigned short* lAp = &lA[cur][0];
    const unsigned short* lBp = &lB[cur][0];
#pragma unroll
    for (int q = 0; q < 4; ++q) {
      if (t + 1 < nt) {  // prefetch pair q of tile t+1 into buf nxt
        gload_lds16(gA + ktn + q * step64, &lA[nxt][q * 4096 + ldsBase]);
        gload_lds16(gB + ktn + q * step64, &lB[nxt][q * 4096 + ldsBase]);
      }
      const int qm = q & 1, qn = q >> 1;
      s16x8 af[4][2], bfr[2][2];
#pragma unroll
      for (int ks = 0; ks < 2; ++ks) {
        const int kph = (ks * 32 + g8) ^ kSw;
#pragma unroll
        for (int m = 0; m < 4; ++m)
          af[m][ks] = *(const s16x8*)
              &lAp[(wr * 128 + qm * 64 + m * 16 + rbase) * 64 + kph];
#pragma unroll
        for (int n = 0; n < 2; ++n)
          bfr[n][ks] = *(const s16x8*)
              &lBp[(wc * 64 + qn * 32 + n * 16 + rbase) * 64 + kph];
      }
      __builtin_amdgcn_s_setprio(1);
#pragma unroll
      for (int m = 0; m < 4; ++m)
#pragma unroll
        for (int n = 0; n < 2; ++n)
#pragma unroll
          for (int ks = 0; ks < 2; ++ks)
            acc[qm * 4 + m][qn * 2 + n] = __builtin_amdgcn_mfma_f32_16x16x32_bf16(
                af[m][ks], bfr[n][ks], acc[qm * 4 + m][qn * 2 + n], 0, 0, 0);
      __builtin_amdgcn_s_setprio(0);
    }
  }

  const int baseRow = row0 + wr * 128 + ((lane >> 4) * 4);
  const int baseCol = col0 + wc * 64 + (lane & 15);
#pragma unroll
  for (int m = 0; m < 8; ++m) {
#pragma unroll
    for (int n = 0; n < 4; ++n) {
      const int colc = baseCol + n * 16;
      if (colc < N) {
        const float bv = bias ? bias[colc] : 0.f;
        const int rowc0 = baseRow + m * 16;
#pragma unroll
        for (int r = 0; r < 4; ++r) {
          float v = acc[m][n][r] + bv;
          if (relu) v = fmaxf(v, 0.f);
          if (outF) outF[(size_t)(rowc0 + r) * ldc + colc] = v;
          if (outB) outB[(size_t)(rowc0 + r) * ldc + colc] = f2bf(v);
        }
      }
    }
  }
}

// ---------------- fused causal attention (flash-style) ----------------
__global__ void __launch_bounds__(256) attn_k(const unsigned short* __restrict__ Q,
                                              const unsigned short* __restrict__ Kb,
                                              const unsigned short* __restrict__ Vt,
                                              unsigned short* __restrict__ O,
                                              int ldq) {
  const int qt = blockIdx.x;
  const int bh = blockIdx.y;
  const int b = bh >> 4, h = bh & 15;
  const int tid = threadIdx.x, wv = tid >> 6, lane = tid & 63;
  const int g = lane >> 4, c = lane & 15;
  __shared__ __align__(16) unsigned short lP[4][16 * 64];
  const int qw0 = qt * 64 + wv * 16;
  s16x8 qf0, qf1;
  {
    const size_t qoff = ((size_t)(b * 1024 + qw0 + c)) * ldq + h * 64 + g * 8;
    qf0 = *(const s16x8*)&Q[qoff];
    qf1 = *(const s16x8*)&Q[qoff + 32];
  }
  f32x4 acc[4] = {};
  float mrun[4], lrun[4];
#pragma unroll
  for (int r = 0; r < 4; ++r) { mrun[r] = -1e30f; lrun[r] = 0.f; }

  for (int kt = 0; kt <= qt; ++kt) {
    f32x4 s[4] = {};
#pragma unroll
    for (int n = 0; n < 4; ++n) {
      const size_t koff = ((size_t)(b * 1024 + kt * 64 + n * 16 + c)) * ldq + h * 64 + g * 8;
      s16x8 k0 = *(const s16x8*)&Kb[koff];
      s16x8 k1 = *(const s16x8*)&Kb[koff + 32];
      s[n] = __builtin_amdgcn_mfma_f32_16x16x32_bf16(qf0, k0, s[n], 0, 0, 0);
      s[n] = __builtin_amdgcn_mfma_f32_16x16x32_bf16(qf1, k1, s[n], 0, 0, 0);
    }
    float p[4][4], mx[4] = {-1e30f, -1e30f, -1e30f, -1e30f};
#pragma unroll
    for (int n = 0; n < 4; ++n)
#pragma unroll
      for (int r = 0; r < 4; ++r) {
        const int qrow = qw0 + g * 4 + r;
        const int key = kt * 64 + n * 16 + c;
        float v = s[n][r] * 0.125f;
        if (key > qrow) v = -1e30f;
        p[n][r] = v;
        mx[r] = fmaxf(mx[r], v);
      }
#pragma unroll
    for (int r = 0; r < 4; ++r)
#pragma unroll
      for (int m = 1; m <= 8; m <<= 1) mx[r] = fmaxf(mx[r], __shfl_xor(mx[r], m));
    float al[4], rs[4];
#pragma unroll
    for (int r = 0; r < 4; ++r) {
      const float mn = fmaxf(mrun[r], mx[r]);
      al[r] = __expf(mrun[r] - mn);
      mrun[r] = mn;
      rs[r] = 0.f;
    }
#pragma unroll
    for (int n = 0; n < 4; ++n)
#pragma unroll
      for (int r = 0; r < 4; ++r) {
        const float e = __expf(p[n][r] - mrun[r]);
        p[n][r] = e;
        rs[r] += e;
      }
#pragma unroll
    for (int r = 0; r < 4; ++r) {
#pragma unroll
      for (int m = 1; m <= 8; m <<= 1) rs[r] += __shfl_xor(rs[r], m);
      lrun[r] = lrun[r] * al[r] + rs[r];
    }
#pragma unroll
    for (int n = 0; n < 4; ++n)
#pragma unroll
      for (int r = 0; r < 4; ++r) acc[n][r] *= al[r];
    __syncthreads();
#pragma unroll
    for (int n = 0; n < 4; ++n)
#pragma unroll
      for (int r = 0; r < 4; ++r)
        lP[wv][(g * 4 + r) * 64 + n * 16 + c] = f2bf(p[n][r]);
    __syncthreads();
    s16x8 pa0 = *(const s16x8*)&lP[wv][c * 64 + g * 8];
    s16x8 pa1 = *(const s16x8*)&lP[wv][c * 64 + 32 + g * 8];
#pragma unroll
    for (int n = 0; n < 4; ++n) {
      const size_t voff = ((size_t)(bh * 64 + n * 16 + c)) * 1024 + kt * 64 + g * 8;
      s16x8 v0 = *(const s16x8*)&Vt[voff];
      s16x8 v1 = *(const s16x8*)&Vt[voff + 32];
      acc[n] = __builtin_amdgcn_mfma_f32_16x16x32_bf16(pa0, v0, acc[n], 0, 0, 0);
      acc[n] = __builtin_amdgcn_mfma_f32_16x16x32_bf16(pa1, v1, acc[n], 0, 0, 0);
    }
  }
#pragma unroll
  for (int n = 0; n < 4; ++n)
#pragma unroll
    for (int r = 0; r < 4; ++r) {
      const size_t row = (size_t)(b * 1024 + qw0 + g * 4 + r);
      O[row * DM + h * 64 + n * 16 + c] = f2bf(acc[n][r] / lrun[r]);
    }
}

// ---------------- host ----------------
extern "C" void kernel_launch(void* const* d_in, const int* in_sizes, int n_in,
                              void* d_out, int out_size, void* d_ws, size_t ws_size,
                              hipStream_t stream) {
  const int* idx = (const int*)d_in[0];
  const float* wte = (const float*)d_in[1];
  const float* wpe = (const float*)d_in[2];
  const float* wq = (const float*)d_in[3];
  const float* wk = (const float*)d_in[4];
  const float* wv = (const float*)d_in[5];
  const float* wo = (const float*)d_in[6];
  const float* bo = (const float*)d_in[7];
  const float* ln1w = (const float*)d_in[8];
  const float* ln1b = (const float*)d_in[9];
  const float* ln2w = (const float*)d_in[10];
  const float* ln2b = (const float*)d_in[11];
  const float* w1 = (const float*)d_in[12];
  const float* b1 = (const float*)d_in[13];
  const float* w2 = (const float*)d_in[14];
  const float* b2 = (const float*)d_in[15];
  const float* lnfw = (const float*)d_in[16];
  const float* lnfb = (const float*)d_in[17];
  const float* wlm = (const float*)d_in[18];
  const float* blm = (const float*)d_in[19];
  float* out = (float*)d_out;

  char* ws = (char*)d_ws;
  size_t off = 0;
  auto alloc = [&](size_t bytes) -> void* {
    void* p = ws + off;
    off += (bytes + 255) & ~(size_t)255;
    return p;
  };
  unsigned short* wqkvT = (unsigned short*)alloc((size_t)NLAYER * 3072 * DM * 2);  // 48MB
  unsigned short* woT = (unsigned short*)alloc((size_t)NLAYER * DM * DM * 2);      // 16MB
  unsigned short* w1T = (unsigned short*)alloc((size_t)NLAYER * DM * DFF2 * 2);    // 64MB
  unsigned short* w2T = (unsigned short*)alloc((size_t)NLAYER * DM * DFF2 * 2);    // 64MB
  // wlmT aliases w1T+w2T (dead after the layer loop): 50432*1024*2 = 103MB <= 128MB
  unsigned short* wlmT = w1T;
  float* X = (float*)alloc((size_t)NTOK * DM * 4);                                 // 16MB
  unsigned short* Hb = (unsigned short*)alloc((size_t)NTOK * DM * 2);              // 8MB
  // union region 32MB: {QKVb 24MB + Ab 8MB} early, {P0 16MB + P1 16MB} at w2
  char* uni = (char*)alloc((size_t)32 * 1024 * 1024);
  unsigned short* QKVb = (unsigned short*)uni;
  unsigned short* Ab = (unsigned short*)(uni + (size_t)24 * 1024 * 1024);
  float* P0 = (float*)uni;
  float* P1 = (float*)(uni + (size_t)16 * 1024 * 1024);
  unsigned short* VtB = (unsigned short*)alloc((size_t)NTOK * DM * 2);             // 8MB
  // Mid: bf16 [4096,4096] between w1/w2; reused (float) as wo split-K partials
  unsigned short* Mid = (unsigned short*)alloc((size_t)NTOK * DFF2 * 2);           // 32MB
  float* MidF = (float*)Mid;

  const size_t qkvStride = (size_t)3072 * DM;
  convT_k<<<dim3(16, 16, 8), 256, 0, stream>>>(wq, wqkvT, DM, DM, qkvStride);
  convT_k<<<dim3(16, 16, 8), 256, 0, stream>>>(wk, wqkvT + (size_t)1024 * DM, DM, DM, qkvStride);
  convT_k<<<dim3(16, 16, 8), 256, 0, stream>>>(wv, wqkvT + (size_t)2048 * DM, DM, DM, qkvStride);
  convT_k<<<dim3(16, 16, 8), 256, 0, stream>>>(wo, woT, DM, DM, (size_t)DM * DM);
  convT_k<<<dim3(64, 16, 8), 256, 0, stream>>>(w1, w1T, DM, DFF2, (size_t)DM * DFF2);
  convT_k<<<dim3(16, 64, 8), 256, 0, stream>>>(w2, w2T, DFF2, DM, (size_t)DM * DFF2);

  embed_k<<<dim3(NTOK), 256, 0, stream>>>(idx, wte, wpe, X);
  ln_k<<<dim3(NTOK), 256, 0, stream>>>(X, ln1w, ln1b, Hb);  // layer-0 ln1

  for (int i = 0; i < NLAYER; ++i) {
    const size_t wOff = (size_t)i * DM * DM;
    const size_t fOff = (size_t)i * DM * DFF2;
    // fused QKV with V-transpose epilogue (V cols -> VtB, not QKVb)
    gemm_k<<<dim3(24, 32), 256, 0, stream>>>(Hb, wqkvT + i * qkvStride, nullptr,
                                             nullptr, QKVb, VtB, NTOK, 3072, DM,
                                             DM, 3072);
    attn_k<<<dim3(16, 64), 256, 0, stream>>>(QKVb, QKVb + 1024, VtB, Ab, 3072);
    // wo: split-K=2, partials into MidF (dead here)
    gemm_k<<<dim3(8, 32, 2), 256, 0, stream>>>(Ab, woT + wOff, nullptr, MidF,
                                               nullptr, nullptr, NTOK, DM,
                                               DM / 2, DM, DM);
    reduce2ln_k<<<dim3(NTOK), 256, 0, stream>>>(X, bo + i * DM, MidF,
                                                MidF + (size_t)NTOK * DM,
                                                ln2w + i * DM, ln2b + i * DM, Hb);
    // w1: 256x256 pipelined kernel, relu, bf16 out
    gemm256_k<<<dim3(16, 16), 512, 0, stream>>>(Hb, w1T + fOff, b1 + i * DFF2,
                                                nullptr, Mid, NTOK, DFF2, DM,
                                                DM, DFF2, 1);
    // w2: split-K=2, partials P0/P1 (union region, free)
    gemm_k<<<dim3(8, 32, 2), 256, 0, stream>>>(Mid, w2T + fOff, nullptr, P0,
                                               nullptr, nullptr, NTOK, DM,
                                               DFF2 / 2, DFF2, DM);
    const float* nw = (i < NLAYER - 1) ? ln1w + (i + 1) * DM : lnfw;
    const float* nb = (i < NLAYER - 1) ? ln1b + (i + 1) * DM : lnfb;
    reduce2ln_k<<<dim3(NTOK), 256, 0, stream>>>(X, b2 + i * DM, P0, P1, nw, nb, Hb);
  }

  // LM head: convert wlm (padded to 50432 rows, aliases dead w1T/w2T), big GEMM
  convT_k<<<dim3(788, 16, 1), 256, 0, stream>>>(wlm, wlmT, DM, NV, 0);
  gemm256_k<<<dim3(197, 16), 512, 0, stream>>>(Hb, wlmT, blm, out, nullptr, NTOK,
                                               NV, DM, DM, NV, 0);
}

// Round 5
// 3330.551 us; speedup vs baseline: 1.5384x; 1.0250x over previous
//
#include <hip/hip_runtime.h>
#include <cstdint>
#include <cstddef>

typedef __attribute__((ext_vector_type(4))) float f32x4;
typedef __attribute__((ext_vector_type(8))) short s16x8;
typedef __attribute__((ext_vector_type(4))) unsigned short u16x4;
typedef __attribute__((ext_vector_type(2))) unsigned short u16x2;

#define NLAYER 8
#define DM 1024
#define NTOK 4096
#define DFF2 4096
#define NV 50257
#define NVPAD 50432  // 197*256, for 256-wide LM tiles

__device__ __forceinline__ unsigned short f2bf(float f) {
  unsigned int u = __float_as_uint(f);
  u = u + 0x7fffu + ((u >> 16) & 1u);
  return (unsigned short)(u >> 16);
}

// CK-style generic->AS1/AS3 conversion for global_load_lds (width 16B).
__device__ __forceinline__ void gload_lds16(const void* gp, void* lp) {
  const __attribute__((address_space(1))) unsigned int* g =
      reinterpret_cast<const __attribute__((address_space(1))) unsigned int*>(
          reinterpret_cast<uintptr_t>(gp));
  __attribute__((address_space(3))) unsigned int* l =
      reinterpret_cast<__attribute__((address_space(3))) unsigned int*>(
          (unsigned int)(uintptr_t)lp);
  __builtin_amdgcn_global_load_lds(g, l, 16, 0, 0);
}

// ---------------- weight convert + transpose: out[n][k] = bf16(in[k][n]) ----
__global__ void __launch_bounds__(256) convT_k(const float* __restrict__ in,
                                               unsigned short* __restrict__ out,
                                               int K, int N, size_t zStride) {
  __shared__ float tile[64][65];
  const int n0 = blockIdx.x * 64, k0 = blockIdx.y * 64;
  const float* inp = in + (size_t)blockIdx.z * K * N;
  unsigned short* outp = out + (size_t)blockIdx.z * zStride;
  const int tid = threadIdx.x;
#pragma unroll
  for (int p = 0; p < 16; ++p) {
    const int r = p * 4 + (tid >> 6);
    const int cc = tid & 63;
    const int gn = n0 + cc;
    tile[r][cc] = (gn < N) ? inp[(size_t)(k0 + r) * N + gn] : 0.f;
  }
  __syncthreads();
#pragma unroll
  for (int p = 0; p < 8; ++p) {
    const int lin = p * 256 + tid;
    const int rn = lin >> 5;
    const int c2 = (lin & 31) * 2;
    u16x2 o;
    o[0] = f2bf(tile[c2][rn]);
    o[1] = f2bf(tile[c2 + 1][rn]);
    *(u16x2*)&outp[(size_t)(n0 + rn) * K + k0 + c2] = o;
  }
}

// ---------------- embedding: x = wte[idx] + wpe[t] ----------------
__global__ void __launch_bounds__(256) embed_k(const int* __restrict__ idx,
                                               const float* __restrict__ wte,
                                               const float* __restrict__ wpe,
                                               float* __restrict__ X) {
  const int tok = blockIdx.x;
  const int t = tok & 1023;
  const int id = idx[tok];
  const int c = threadIdx.x * 4;
  f32x4 a = *(const f32x4*)&wte[(size_t)id * DM + c];
  f32x4 p = *(const f32x4*)&wpe[(size_t)t * DM + c];
  a = a + p;
  *(f32x4*)&X[(size_t)tok * DM + c] = a;
}

// ---------------- LayerNorm: f32 in -> bf16 out ----------------
__global__ void __launch_bounds__(256) ln_k(const float* __restrict__ X,
                                            const float* __restrict__ W,
                                            const float* __restrict__ Bp,
                                            unsigned short* __restrict__ O) {
  const int row = blockIdx.x, tid = threadIdx.x;
  const size_t base = (size_t)row * DM;
  f32x4 v = *(const f32x4*)&X[base + tid * 4];
  float s = v[0] + v[1] + v[2] + v[3];
  float q = v[0] * v[0] + v[1] * v[1] + v[2] * v[2] + v[3] * v[3];
#pragma unroll
  for (int m = 1; m < 64; m <<= 1) {
    s += __shfl_xor(s, m);
    q += __shfl_xor(q, m);
  }
  __shared__ float ps[4], pq[4];
  const int wv = tid >> 6;
  if ((tid & 63) == 0) { ps[wv] = s; pq[wv] = q; }
  __syncthreads();
  s = ps[0] + ps[1] + ps[2] + ps[3];
  q = pq[0] + pq[1] + pq[2] + pq[3];
  const float mu = s * (1.f / DM);
  const float var = q * (1.f / DM) - mu * mu;
  const float rstd = rsqrtf(var + 1e-5f);
  f32x4 w = *(const f32x4*)&W[tid * 4];
  f32x4 bb = *(const f32x4*)&Bp[tid * 4];
  u16x4 o;
#pragma unroll
  for (int j = 0; j < 4; ++j) o[j] = f2bf((v[j] - mu) * rstd * w[j] + bb[j]);
  *(u16x4*)&O[base + tid * 4] = o;
}

// -------- fused: X += bias + P0 + P1; then LN(X) -> bf16 O --------
__global__ void __launch_bounds__(256) reduce2ln_k(
    float* __restrict__ X, const float* __restrict__ bias,
    const float* __restrict__ P0, const float* __restrict__ P1,
    const float* __restrict__ W, const float* __restrict__ Bp,
    unsigned short* __restrict__ O) {
  const int row = blockIdx.x, tid = threadIdx.x;
  const size_t base = (size_t)row * DM;
  const size_t i = base + tid * 4;
  f32x4 v = *(f32x4*)&X[i];
  {
    f32x4 b = *(const f32x4*)&bias[tid * 4];
    f32x4 a = *(const f32x4*)&P0[i];
    f32x4 c = *(const f32x4*)&P1[i];
    v = v + b + a + c;
    *(f32x4*)&X[i] = v;
  }
  float s = v[0] + v[1] + v[2] + v[3];
  float q = v[0] * v[0] + v[1] * v[1] + v[2] * v[2] + v[3] * v[3];
#pragma unroll
  for (int m = 1; m < 64; m <<= 1) {
    s += __shfl_xor(s, m);
    q += __shfl_xor(q, m);
  }
  __shared__ float ps[4], pq[4];
  const int wv = tid >> 6;
  if ((tid & 63) == 0) { ps[wv] = s; pq[wv] = q; }
  __syncthreads();
  s = ps[0] + ps[1] + ps[2] + ps[3];
  q = pq[0] + pq[1] + pq[2] + pq[3];
  const float mu = s * (1.f / DM);
  const float var = q * (1.f / DM) - mu * mu;
  const float rstd = rsqrtf(var + 1e-5f);
  f32x4 w = *(const f32x4*)&W[tid * 4];
  f32x4 bb = *(const f32x4*)&Bp[tid * 4];
  u16x4 o;
#pragma unroll
  for (int j = 0; j < 4; ++j) o[j] = f2bf((v[j] - mu) * rstd * w[j] + bb[j]);
  *(u16x4*)&O[base + tid * 4] = o;
}

// ---------------- GEMM 128x128 (m97 structure, BK=64, XOR-swizzled LDS) ----
__global__ void __launch_bounds__(256) gemm_k(
    const unsigned short* __restrict__ A, const unsigned short* __restrict__ Bt,
    const float* __restrict__ bias, float* __restrict__ outF,
    unsigned short* __restrict__ outB, int M, int N, int K, int lda, int ldc) {
  __shared__ __align__(16) unsigned short lA[128 * 64];
  __shared__ __align__(16) unsigned short lB[128 * 64];
  const int tid = threadIdx.x;
  const int wv = tid >> 6, lane = tid & 63;
  const int row0 = blockIdx.y * 128, col0 = blockIdx.x * 128;
  const int wr = wv >> 1, wc = wv & 1;

  const int z = blockIdx.z;
  A += (size_t)z * K;
  Bt += (size_t)z * K;
  if (gridDim.z > 1) outF += (size_t)z * M * ldc;

  f32x4 acc[4][4] = {};

  const int sRow = tid >> 3;                              // 0..31
  const int sColSw = ((tid & 7) * 8) ^ ((sRow & 7) * 8);  // elements, [0,64)
  const unsigned short* gA = A + (size_t)(row0 + sRow) * lda + sColSw;
  const unsigned short* gB = Bt + (size_t)(col0 + sRow) * lda + sColSw;
  unsigned short* lAd = lA + tid * 8;
  unsigned short* lBd = lB + tid * 8;
  const size_t step32 = (size_t)32 * lda;

  const int rbase = lane & 15;
  const int kHi = (lane >> 4) * 8;
  const int kSw = (lane & 7) * 8;

  for (int kt = 0; kt < K; kt += 64) {
#pragma unroll
    for (int i = 0; i < 4; ++i) {
      gload_lds16(gA + kt + i * step32, lAd + i * 2048);
      gload_lds16(gB + kt + i * step32, lBd + i * 2048);
    }
    __syncthreads();
    s16x8 af[2][4], bfr[2][4];
#pragma unroll
    for (int kk = 0; kk < 2; ++kk) {
      const int kph = (kk * 32 + kHi) ^ kSw;
#pragma unroll
      for (int m = 0; m < 4; ++m)
        af[kk][m] = *(const s16x8*)&lA[(wr * 64 + m * 16 + rbase) * 64 + kph];
#pragma unroll
      for (int n = 0; n < 4; ++n)
        bfr[kk][n] = *(const s16x8*)&lB[(wc * 64 + n * 16 + rbase) * 64 + kph];
    }
#pragma unroll
    for (int kk = 0; kk < 2; ++kk)
#pragma unroll
      for (int m = 0; m < 4; ++m)
#pragma unroll
        for (int n = 0; n < 4; ++n)
          acc[m][n] = __builtin_amdgcn_mfma_f32_16x16x32_bf16(
              af[kk][m], bfr[kk][n], acc[m][n], 0, 0, 0);
    __syncthreads();
  }

  const int baseRow = row0 + wr * 64 + ((lane >> 4) * 4);
  const int baseCol = col0 + wc * 64 + (lane & 15);
#pragma unroll
  for (int m = 0; m < 4; ++m) {
#pragma unroll
    for (int n = 0; n < 4; ++n) {
      const int colc = baseCol + n * 16;
      if (colc < N) {
        const float bv = bias ? bias[colc] : 0.f;
        const int rowc0 = baseRow + m * 16;
#pragma unroll
        for (int r = 0; r < 4; ++r) {
          float v = acc[m][n][r] + bv;
          if (outF) outF[(size_t)(rowc0 + r) * ldc + colc] = v;
          if (outB) outB[(size_t)(rowc0 + r) * ldc + colc] = f2bf(v);
        }
      }
    }
  }
}

// ------- GEMM 256x256 pipelined: BK=32, 4-deep LDS ring, counted vmcnt -----
// Per K-tile (32): two phases of {ds_read frags || stage tile t+3 half ||
// setprio(1) 16 MFMA setprio(0)}; boundary = vmcnt(8) + raw s_barrier (tile
// t+1's 4 loads are the oldest 4 of <=12 outstanding -> landed). vmcnt(0)
// once at t==nt-4, then dry epilogue tiles. LDS [buf][A|B][256r][32c] with
// group swizzle g^=(row>>1)&3: exact 2-way banks (free). Write side via
// pre-swizzled global source + linear gload dest (both-sides rule).
// Optional fused V-transpose epilogue (QKV): cols >= 2048 -> vt[bh][hs][t].
__global__ void __launch_bounds__(512, 2) gemm256p_k(
    const unsigned short* __restrict__ A, const unsigned short* __restrict__ Bt,
    const float* __restrict__ bias, float* __restrict__ outF,
    unsigned short* __restrict__ outB, unsigned short* __restrict__ vt,
    int M, int N, int K, int lda, int ldc, int relu) {
  __shared__ __align__(16) unsigned short lds[4][2][8192];
  const int tid = threadIdx.x;  // 0..511
  const int wv = tid >> 6, lane = tid & 63;
  const int row0 = blockIdx.y * 256, col0 = blockIdx.x * 256;
  const int wr = wv >> 2, wc = wv & 3;  // 2x4 waves; wave tile 128x64

  f32x4 acc[8][4] = {};

  // staging: thread t -> LDS row (chunk*128 + t>>2), 8-elem group (t&3);
  // global source group pre-swizzled: (t&3) ^ ((t>>3)&3)  [row>>1 & 3]
  const int sRow = tid >> 2;  // 0..127 (chunk 0)
  const int sCol = ((tid & 3) ^ ((tid >> 3) & 3)) * 8;
  const unsigned short* gA = A + (size_t)(row0 + sRow) * lda + sCol;
  const unsigned short* gB = Bt + (size_t)(col0 + sRow) * lda + sCol;
  const size_t step128 = (size_t)128 * lda;

  const int rbase = lane & 15;
  const int grp = ((lane >> 4) ^ ((lane >> 1) & 3)) * 8;  // swizzled k-group

  const int nt = K >> 5;

#define STG(t, x, g)                                              \
  {                                                               \
    unsigned short* d = &lds[(t) & 3][x][tid * 8];                \
    gload_lds16((g) + (size_t)(t) * 32, d);                       \
    gload_lds16((g) + (size_t)(t) * 32 + step128, d + 4096);      \
  }

  // prologue: stage tiles 0,1,2 (12 loads); wait oldest 4 (= tile 0)
  STG(0, 0, gA); STG(0, 1, gB);
  STG(1, 0, gA); STG(1, 1, gB);
  STG(2, 0, gA); STG(2, 1, gB);
  asm volatile("s_waitcnt vmcnt(8)" ::: "memory");
  __builtin_amdgcn_s_barrier();

  for (int t = 0; t < nt; ++t) {
    const unsigned short* la = &lds[t & 3][0][0];
    const unsigned short* lb = &lds[t & 3][1][0];
    s16x8 bf[4], af[4];
    // phase A: B frags (kept for both phases) + A frags rows [0,64)
#pragma unroll
    for (int n = 0; n < 4; ++n)
      bf[n] = *(const s16x8*)&lb[(wc * 64 + n * 16 + rbase) * 32 + grp];
#pragma unroll
    for (int m = 0; m < 4; ++m)
      af[m] = *(const s16x8*)&la[(wr * 128 + m * 16 + rbase) * 32 + grp];
    if (t + 3 < nt) STG(t + 3, 0, gA);  // writes buf (t-1)&3: readers done
    __builtin_amdgcn_s_setprio(1);
#pragma unroll
    for (int m = 0; m < 4; ++m)
#pragma unroll
      for (int n = 0; n < 4; ++n)
        acc[m][n] = __builtin_amdgcn_mfma_f32_16x16x32_bf16(af[m], bf[n],
                                                            acc[m][n], 0, 0, 0);
    __builtin_amdgcn_s_setprio(0);
    // phase B: A frags rows [64,128)
#pragma unroll
    for (int m = 0; m < 4; ++m)
      af[m] = *(const s16x8*)&la[(wr * 128 + 64 + m * 16 + rbase) * 32 + grp];
    if (t + 3 < nt) STG(t + 3, 1, gB);
    __builtin_amdgcn_s_setprio(1);
#pragma unroll
    for (int m = 0; m < 4; ++m)
#pragma unroll
      for (int n = 0; n < 4; ++n)
        acc[4 + m][n] = __builtin_amdgcn_mfma_f32_16x16x32_bf16(
            af[m], bf[n], acc[4 + m][n], 0, 0, 0);
    __builtin_amdgcn_s_setprio(0);
    // boundary: tile t+1 = oldest 4 of <=12 outstanding loads
    if (t < nt - 4)
      asm volatile("s_waitcnt vmcnt(8)" ::: "memory");
    else if (t == nt - 4)
      asm volatile("s_waitcnt vmcnt(0)" ::: "memory");
    __builtin_amdgcn_s_barrier();
  }
#undef STG

  const int baseRow = row0 + wr * 128 + ((lane >> 4) * 4);
  const int baseCol = col0 + wc * 64 + (lane & 15);
#pragma unroll
  for (int m = 0; m < 8; ++m) {
#pragma unroll
    for (int n = 0; n < 4; ++n) {
      const int colc = baseCol + n * 16;
      if (colc < N) {
        const int rowc0 = baseRow + m * 16;
        if (vt && colc >= 2048) {
          const int f = colc - 2048;
          const int b = rowc0 >> 10, t0 = rowc0 & 1023;
          u16x4 o;
#pragma unroll
          for (int r = 0; r < 4; ++r) o[r] = f2bf(acc[m][n][r]);
          *(u16x4*)&vt[((size_t)((b << 4) + (f >> 6)) * 64 + (f & 63)) * 1024 + t0] = o;
        } else {
          const float bv = bias ? bias[colc] : 0.f;
#pragma unroll
          for (int r = 0; r < 4; ++r) {
            float v = acc[m][n][r] + bv;
            if (relu) v = fmaxf(v, 0.f);
            if (outF) outF[(size_t)(rowc0 + r) * ldc + colc] = v;
            if (outB) outB[(size_t)(rowc0 + r) * ldc + colc] = f2bf(v);
          }
        }
      }
    }
  }
}

// ---------------- fused causal attention (flash-style) ----------------
__global__ void __launch_bounds__(256) attn_k(const unsigned short* __restrict__ Q,
                                              const unsigned short* __restrict__ Kb,
                                              const unsigned short* __restrict__ Vt,
                                              unsigned short* __restrict__ O,
                                              int ldq) {
  const int qt = blockIdx.x;
  const int bh = blockIdx.y;
  const int b = bh >> 4, h = bh & 15;
  const int tid = threadIdx.x, wv = tid >> 6, lane = tid & 63;
  const int g = lane >> 4, c = lane & 15;
  __shared__ __align__(16) unsigned short lP[4][16 * 64];
  const int qw0 = qt * 64 + wv * 16;
  s16x8 qf0, qf1;
  {
    const size_t qoff = ((size_t)(b * 1024 + qw0 + c)) * ldq + h * 64 + g * 8;
    qf0 = *(const s16x8*)&Q[qoff];
    qf1 = *(const s16x8*)&Q[qoff + 32];
  }
  f32x4 acc[4] = {};
  float mrun[4], lrun[4];
#pragma unroll
  for (int r = 0; r < 4; ++r) { mrun[r] = -1e30f; lrun[r] = 0.f; }

  for (int kt = 0; kt <= qt; ++kt) {
    f32x4 s[4] = {};
#pragma unroll
    for (int n = 0; n < 4; ++n) {
      const size_t koff = ((size_t)(b * 1024 + kt * 64 + n * 16 + c)) * ldq + h * 64 + g * 8;
      s16x8 k0 = *(const s16x8*)&Kb[koff];
      s16x8 k1 = *(const s16x8*)&Kb[koff + 32];
      s[n] = __builtin_amdgcn_mfma_f32_16x16x32_bf16(qf0, k0, s[n], 0, 0, 0);
      s[n] = __builtin_amdgcn_mfma_f32_16x16x32_bf16(qf1, k1, s[n], 0, 0, 0);
    }
    float p[4][4], mx[4] = {-1e30f, -1e30f, -1e30f, -1e30f};
#pragma unroll
    for (int n = 0; n < 4; ++n)
#pragma unroll
      for (int r = 0; r < 4; ++r) {
        const int qrow = qw0 + g * 4 + r;
        const int key = kt * 64 + n * 16 + c;
        float v = s[n][r] * 0.125f;
        if (key > qrow) v = -1e30f;
        p[n][r] = v;
        mx[r] = fmaxf(mx[r], v);
      }
#pragma unroll
    for (int r = 0; r < 4; ++r)
#pragma unroll
      for (int m = 1; m <= 8; m <<= 1) mx[r] = fmaxf(mx[r], __shfl_xor(mx[r], m));
    float al[4], rs[4];
#pragma unroll
    for (int r = 0; r < 4; ++r) {
      const float mn = fmaxf(mrun[r], mx[r]);
      al[r] = __expf(mrun[r] - mn);
      mrun[r] = mn;
      rs[r] = 0.f;
    }
#pragma unroll
    for (int n = 0; n < 4; ++n)
#pragma unroll
      for (int r = 0; r < 4; ++r) {
        const float e = __expf(p[n][r] - mrun[r]);
        p[n][r] = e;
        rs[r] += e;
      }
#pragma unroll
    for (int r = 0; r < 4; ++r) {
#pragma unroll
      for (int m = 1; m <= 8; m <<= 1) rs[r] += __shfl_xor(rs[r], m);
      lrun[r] = lrun[r] * al[r] + rs[r];
    }
#pragma unroll
    for (int n = 0; n < 4; ++n)
#pragma unroll
      for (int r = 0; r < 4; ++r) acc[n][r] *= al[r];
    __syncthreads();
#pragma unroll
    for (int n = 0; n < 4; ++n)
#pragma unroll
      for (int r = 0; r < 4; ++r)
        lP[wv][(g * 4 + r) * 64 + n * 16 + c] = f2bf(p[n][r]);
    __syncthreads();
    s16x8 pa0 = *(const s16x8*)&lP[wv][c * 64 + g * 8];
    s16x8 pa1 = *(const s16x8*)&lP[wv][c * 64 + 32 + g * 8];
#pragma unroll
    for (int n = 0; n < 4; ++n) {
      const size_t voff = ((size_t)(bh * 64 + n * 16 + c)) * 1024 + kt * 64 + g * 8;
      s16x8 v0 = *(const s16x8*)&Vt[voff];
      s16x8 v1 = *(const s16x8*)&Vt[voff + 32];
      acc[n] = __builtin_amdgcn_mfma_f32_16x16x32_bf16(pa0, v0, acc[n], 0, 0, 0);
      acc[n] = __builtin_amdgcn_mfma_f32_16x16x32_bf16(pa1, v1, acc[n], 0, 0, 0);
    }
  }
#pragma unroll
  for (int n = 0; n < 4; ++n)
#pragma unroll
    for (int r = 0; r < 4; ++r) {
      const size_t row = (size_t)(b * 1024 + qw0 + g * 4 + r);
      O[row * DM + h * 64 + n * 16 + c] = f2bf(acc[n][r] / lrun[r]);
    }
}

// ---------------- host ----------------
extern "C" void kernel_launch(void* const* d_in, const int* in_sizes, int n_in,
                              void* d_out, int out_size, void* d_ws, size_t ws_size,
                              hipStream_t stream) {
  const int* idx = (const int*)d_in[0];
  const float* wte = (const float*)d_in[1];
  const float* wpe = (const float*)d_in[2];
  const float* wq = (const float*)d_in[3];
  const float* wk = (const float*)d_in[4];
  const float* wv = (const float*)d_in[5];
  const float* wo = (const float*)d_in[6];
  const float* bo = (const float*)d_in[7];
  const float* ln1w = (const float*)d_in[8];
  const float* ln1b = (const float*)d_in[9];
  const float* ln2w = (const float*)d_in[10];
  const float* ln2b = (const float*)d_in[11];
  const float* w1 = (const float*)d_in[12];
  const float* b1 = (const float*)d_in[13];
  const float* w2 = (const float*)d_in[14];
  const float* b2 = (const float*)d_in[15];
  const float* lnfw = (const float*)d_in[16];
  const float* lnfb = (const float*)d_in[17];
  const float* wlm = (const float*)d_in[18];
  const float* blm = (const float*)d_in[19];
  float* out = (float*)d_out;

  char* ws = (char*)d_ws;
  size_t off = 0;
  auto alloc = [&](size_t bytes) -> void* {
    void* p = ws + off;
    off += (bytes + 255) & ~(size_t)255;
    return p;
  };
  unsigned short* wqkvT = (unsigned short*)alloc((size_t)NLAYER * 3072 * DM * 2);  // 48MB
  unsigned short* woT = (unsigned short*)alloc((size_t)NLAYER * DM * DM * 2);      // 16MB
  unsigned short* w1T = (unsigned short*)alloc((size_t)NLAYER * DM * DFF2 * 2);    // 64MB
  unsigned short* w2T = (unsigned short*)alloc((size_t)NLAYER * DM * DFF2 * 2);    // 64MB
  // wlmT aliases w1T+w2T (dead after the layer loop): 50432*1024*2 = 103MB <= 128MB
  unsigned short* wlmT = w1T;
  float* X = (float*)alloc((size_t)NTOK * DM * 4);                                 // 16MB
  unsigned short* Hb = (unsigned short*)alloc((size_t)NTOK * DM * 2);              // 8MB
  // union region 32MB: {QKVb 24MB + Ab 8MB} early, {P0 16MB + P1 16MB} at w2
  char* uni = (char*)alloc((size_t)32 * 1024 * 1024);
  unsigned short* QKVb = (unsigned short*)uni;
  unsigned short* Ab = (unsigned short*)(uni + (size_t)24 * 1024 * 1024);
  float* P0 = (float*)uni;
  float* P1 = (float*)(uni + (size_t)16 * 1024 * 1024);
  unsigned short* VtB = (unsigned short*)alloc((size_t)NTOK * DM * 2);             // 8MB
  unsigned short* Mid = (unsigned short*)alloc((size_t)NTOK * DFF2 * 2);           // 32MB
  float* MidF = (float*)Mid;

  const size_t qkvStride = (size_t)3072 * DM;
  convT_k<<<dim3(16, 16, 8), 256, 0, stream>>>(wq, wqkvT, DM, DM, qkvStride);
  convT_k<<<dim3(16, 16, 8), 256, 0, stream>>>(wk, wqkvT + (size_t)1024 * DM, DM, DM, qkvStride);
  convT_k<<<dim3(16, 16, 8), 256, 0, stream>>>(wv, wqkvT + (size_t)2048 * DM, DM, DM, qkvStride);
  convT_k<<<dim3(16, 16, 8), 256, 0, stream>>>(wo, woT, DM, DM, (size_t)DM * DM);
  convT_k<<<dim3(64, 16, 8), 256, 0, stream>>>(w1, w1T, DM, DFF2, (size_t)DM * DFF2);
  convT_k<<<dim3(16, 64, 8), 256, 0, stream>>>(w2, w2T, DFF2, DM, (size_t)DM * DFF2);

  embed_k<<<dim3(NTOK), 256, 0, stream>>>(idx, wte, wpe, X);
  ln_k<<<dim3(NTOK), 256, 0, stream>>>(X, ln1w, ln1b, Hb);  // layer-0 ln1

  for (int i = 0; i < NLAYER; ++i) {
    const size_t wOff = (size_t)i * DM * DM;
    const size_t fOff = (size_t)i * DM * DFF2;
    // fused QKV (pipelined 256^2) with V-transpose epilogue
    gemm256p_k<<<dim3(12, 16), 512, 0, stream>>>(Hb, wqkvT + i * qkvStride,
                                                 nullptr, nullptr, QKVb, VtB,
                                                 NTOK, 3072, DM, DM, 3072, 0);
    attn_k<<<dim3(16, 64), 256, 0, stream>>>(QKVb, QKVb + 1024, VtB, Ab, 3072);
    // wo: split-K=2, partials into MidF (dead here)
    gemm_k<<<dim3(8, 32, 2), 256, 0, stream>>>(Ab, woT + wOff, nullptr, MidF,
                                               nullptr, NTOK, DM, DM / 2, DM, DM);
    reduce2ln_k<<<dim3(NTOK), 256, 0, stream>>>(X, bo + i * DM, MidF,
                                                MidF + (size_t)NTOK * DM,
                                                ln2w + i * DM, ln2b + i * DM, Hb);
    // w1: pipelined 256^2, relu, bf16 out
    gemm256p_k<<<dim3(16, 16), 512, 0, stream>>>(Hb, w1T + fOff, b1 + i * DFF2,
                                                 nullptr, Mid, nullptr, NTOK,
                                                 DFF2, DM, DM, DFF2, 1);
    // w2: split-K=2, partials P0/P1 (union region, free)
    gemm_k<<<dim3(8, 32, 2), 256, 0, stream>>>(Mid, w2T + fOff, nullptr, P0,
                                               nullptr, NTOK, DM, DFF2 / 2,
                                               DFF2, DM);
    const float* nw = (i < NLAYER - 1) ? ln1w + (i + 1) * DM : lnfw;
    const float* nb = (i < NLAYER - 1) ? ln1b + (i + 1) * DM : lnfb;
    reduce2ln_k<<<dim3(NTOK), 256, 0, stream>>>(X, b2 + i * DM, P0, P1, nw, nb, Hb);
  }

  // LM head: convert wlm (padded to 50432 rows, aliases dead w1T/w2T), big GEMM
  convT_k<<<dim3(788, 16, 1), 256, 0, stream>>>(wlm, wlmT, DM, NV, 0);
  gemm256p_k<<<dim3(197, 16), 512, 0, stream>>>(Hb, wlmT, blm, out, nullptr,
                                                nullptr, NTOK, NV, DM, DM, NV, 0);
}